// Round 2
// baseline (4881.713 us; speedup 1.0000x reference)
//
#include <hip/hip_runtime.h>

// RT-DETR decoder, round 1: resubmission of round-0 baseline (round 0 hit a
// GPU-broker acquisition timeout; no data). Correctness-first fp32.
// Strategy: one generic tiled GEMM (64x64 tile, BK=16, 256 thr, 4x4/thread),
// dedicated kernels for MHA (scores/softmax/PV), MSDA gather, LN, PE, heads.
// Workspace: 69.6MB arena (val, aliased with pe/qkv/scores/qposh) + ~33MB bufs.

static constexpr int kB = 8, kQ = 300, kC = 256, kH = 8, kL = 6,
                     kF = 1024, kNC = 80, kS = 8500;
static constexpr int kBQ = kB * kQ;  // 2400

// ---------------- generic GEMM: out = act(A@W + bias) ----------------
__global__ __launch_bounds__(256) void gemm_f32(
    const float* __restrict__ A, const float* __restrict__ W,
    const float* __restrict__ bias, float* __restrict__ out,
    int M, int N, int K, int act)
{
  __shared__ float As[16][65];
  __shared__ float Ws[16][65];
  int tid = threadIdx.x;
  int tn = blockIdx.x * 64, tm = blockIdx.y * 64;
  int ty = tid >> 4, tx = tid & 15;
  float acc[4][4] = {};
  for (int k0 = 0; k0 < K; k0 += 16) {
    {
      int r = tid >> 2, kk = (tid & 3) * 4;
      int row = tm + r;
      float4 v = make_float4(0.f, 0.f, 0.f, 0.f);
      if (row < M) v = *reinterpret_cast<const float4*>(A + (size_t)row * K + k0 + kk);
      As[kk + 0][r] = v.x; As[kk + 1][r] = v.y; As[kk + 2][r] = v.z; As[kk + 3][r] = v.w;
    }
    {
      int kk = tid >> 4, c = (tid & 15) * 4;
      int col = tn + c;
      const float* wp = W + (size_t)(k0 + kk) * N + col;
      float4 v = make_float4(0.f, 0.f, 0.f, 0.f);
      if (col + 3 < N) v = *reinterpret_cast<const float4*>(wp);
      else {
        if (col + 0 < N) v.x = wp[0];
        if (col + 1 < N) v.y = wp[1];
        if (col + 2 < N) v.z = wp[2];
      }
      Ws[kk][c + 0] = v.x; Ws[kk][c + 1] = v.y; Ws[kk][c + 2] = v.z; Ws[kk][c + 3] = v.w;
    }
    __syncthreads();
#pragma unroll
    for (int k = 0; k < 16; ++k) {
      float a[4], b[4];
#pragma unroll
      for (int i = 0; i < 4; ++i) a[i] = As[k][ty * 4 + i];
#pragma unroll
      for (int j = 0; j < 4; ++j) b[j] = Ws[k][tx * 4 + j];
#pragma unroll
      for (int i = 0; i < 4; ++i)
#pragma unroll
        for (int j = 0; j < 4; ++j) acc[i][j] += a[i] * b[j];
    }
    __syncthreads();
  }
#pragma unroll
  for (int i = 0; i < 4; ++i) {
    int row = tm + ty * 4 + i;
    if (row >= M) continue;
#pragma unroll
    for (int j = 0; j < 4; ++j) {
      int col = tn + tx * 4 + j;
      if (col >= N) continue;
      float v = acc[i][j] + (bias ? bias[col] : 0.f);
      if (act) v = fmaxf(v, 0.f);
      out[(size_t)row * N + col] = v;
    }
  }
}

// ---------------- LayerNorm: out = LN(x + delta) * g + b ----------------
__global__ __launch_bounds__(256) void ln_kernel(
    const float* __restrict__ x, const float* __restrict__ delta,
    const float* __restrict__ g, const float* __restrict__ b,
    float* __restrict__ out)
{
  __shared__ float red[4];
  int row = blockIdx.x, t = threadIdx.x;
  size_t idx = (size_t)row * 256 + t;
  float v = x[idx] + (delta ? delta[idx] : 0.f);
  float s = v;
#pragma unroll
  for (int o = 32; o; o >>= 1) s += __shfl_xor(s, o);
  if ((t & 63) == 0) red[t >> 6] = s;
  __syncthreads();
  float mean = (red[0] + red[1] + red[2] + red[3]) * (1.f / 256.f);
  __syncthreads();
  float dv = v - mean;
  float s2 = dv * dv;
#pragma unroll
  for (int o = 32; o; o >>= 1) s2 += __shfl_xor(s2, o);
  if ((t & 63) == 0) red[t >> 6] = s2;
  __syncthreads();
  float var = (red[0] + red[1] + red[2] + red[3]) * (1.f / 256.f);
  out[idx] = dv * rsqrtf(var + 1e-5f) * g[t] + b[t];
}

__global__ void add_kernel(const float* __restrict__ a, const float* __restrict__ b,
                           float* __restrict__ o, int n)
{
  int i = blockIdx.x * 256 + threadIdx.x;
  if (i < n) o[i] = a[i] + b[i];
}

__global__ void sigmoid_kernel(const float* __restrict__ x, float* __restrict__ o, int n)
{
  int i = blockIdx.x * 256 + threadIdx.x;
  if (i < n) o[i] = 1.f / (1.f + expf(-x[i]));
}

// ---------------- sine positional embedding (B,Q,512) ----------------
__global__ void pe_kernel(const float* __restrict__ ref, const float* __restrict__ vr,
                          float* __restrict__ pe)
{
  int idx = blockIdx.x * 256 + threadIdx.x;
  if (idx >= kBQ * 512) return;
  int ch = idx & 511, bq = idx >> 9;
  int b = bq / kQ;
  int c = ch >> 7, j = ch & 127, p = j >> 1;
  // qsrc = ref * valid_ratio(level 0)
  float pos = ref[bq * 4 + c] * vr[(b * 4 + 0) * 2 + (c & 1)];
  float dim = expf((float)p * (9.210340371976184f / 64.f));  // 10000^(p/64)
  float arg = pos * 6.283185307179586f / dim;
  pe[idx] = (j & 1) ? cosf(arg) : sinf(arg);
}

// ---------------- MHA: scores = q.k^T * scale ----------------
__global__ __launch_bounds__(256) void attn_scores(const float* __restrict__ qkv,
                                                   float* __restrict__ sc)
{
  int bh = blockIdx.z;
  int b = bh >> 3, h = bh & 7;
  int qt = blockIdx.y * 32, kt = blockIdx.x * 32;
  __shared__ float qs[32][33], ks[32][33];
  int r = threadIdx.x >> 3, dd = (threadIdx.x & 7) * 4;
  {
    int qi = qt + r;
    float4 v = make_float4(0.f, 0.f, 0.f, 0.f);
    if (qi < kQ) v = *reinterpret_cast<const float4*>(qkv + (size_t)(b * kQ + qi) * 768 + h * 32 + dd);
    qs[r][dd] = v.x; qs[r][dd + 1] = v.y; qs[r][dd + 2] = v.z; qs[r][dd + 3] = v.w;
    int kj = kt + r;
    float4 w = make_float4(0.f, 0.f, 0.f, 0.f);
    if (kj < kQ) w = *reinterpret_cast<const float4*>(qkv + (size_t)(b * kQ + kj) * 768 + 256 + h * 32 + dd);
    ks[r][dd] = w.x; ks[r][dd + 1] = w.y; ks[r][dd + 2] = w.z; ks[r][dd + 3] = w.w;
  }
  __syncthreads();
  int ty = (threadIdx.x >> 4) * 2, tx = (threadIdx.x & 15) * 2;
  float acc[2][2] = {};
#pragma unroll
  for (int k = 0; k < 32; ++k) {
    float a0 = qs[ty][k], a1 = qs[ty + 1][k];
    float b0 = ks[tx][k], b1 = ks[tx + 1][k];
    acc[0][0] += a0 * b0; acc[0][1] += a0 * b1;
    acc[1][0] += a1 * b0; acc[1][1] += a1 * b1;
  }
  const float scale = 0.17677669529663687f;  // 1/sqrt(32)
#pragma unroll
  for (int i = 0; i < 2; ++i) {
    int qi = qt + ty + i;
    if (qi >= kQ) continue;
#pragma unroll
    for (int j = 0; j < 2; ++j) {
      int kj = kt + tx + j;
      if (kj >= kQ) continue;
      sc[((size_t)bh * kQ + qi) * kQ + kj] = acc[i][j] * scale;
    }
  }
}

// one wave per row of 300
__global__ __launch_bounds__(256) void softmax_rows(float* __restrict__ sc)
{
  int wid = blockIdx.x * 4 + (threadIdx.x >> 6);
  int lane = threadIdx.x & 63;
  float* row = sc + (size_t)wid * kQ;
  float v[5];
  float m = -1e30f;
#pragma unroll
  for (int i = 0; i < 5; ++i) {
    int idx = lane + i * 64;
    v[i] = (idx < kQ) ? row[idx] : -1e30f;
    m = fmaxf(m, v[i]);
  }
#pragma unroll
  for (int o = 32; o; o >>= 1) m = fmaxf(m, __shfl_xor(m, o));
  float s = 0.f;
#pragma unroll
  for (int i = 0; i < 5; ++i) { v[i] = expf(v[i] - m); s += v[i]; }
#pragma unroll
  for (int o = 32; o; o >>= 1) s += __shfl_xor(s, o);
  float inv = 1.f / s;
#pragma unroll
  for (int i = 0; i < 5; ++i) {
    int idx = lane + i * 64;
    if (idx < kQ) row[idx] = v[i] * inv;
  }
}

// out[b,q,h*32+d] = sum_k att[b,h,q,k] * v[b,k,h,d]; V staged in LDS
__global__ __launch_bounds__(256) void attn_pv(const float* __restrict__ qkv,
                                               const float* __restrict__ att,
                                               float* __restrict__ outp)
{
  int bh = blockIdx.y;
  int b = bh >> 3, h = bh & 7;
  __shared__ float vs[300][32];
  int d = threadIdx.x & 31;
  for (int k = threadIdx.x >> 5; k < kQ; k += 8)
    vs[k][d] = qkv[(size_t)(b * kQ + k) * 768 + 512 + h * 32 + d];
  __syncthreads();
  int qr = threadIdx.x >> 5;
  int qend = (kQ < (int)(blockIdx.x * 64 + 64)) ? kQ : (int)(blockIdx.x * 64 + 64);
  for (int q = blockIdx.x * 64 + qr; q < qend; q += 8) {
    const float* arow = att + ((size_t)bh * kQ + q) * kQ;
    float acc = 0.f;
    for (int k = 0; k < kQ; ++k) acc += arow[k] * vs[k][d];
    outp[(size_t)(b * kQ + q) * 256 + h * 32 + d] = acc;
  }
}

// softmax over NL*P=16 for attention weights, one thread per (b,q,h)
__global__ void softmax16_kernel(float* __restrict__ x)
{
  int r = blockIdx.x * 256 + threadIdx.x;
  if (r >= kBQ * kH) return;
  float* p = x + (size_t)r * 16;
  float m = -1e30f;
#pragma unroll
  for (int k = 0; k < 16; ++k) m = fmaxf(m, p[k]);
  float s = 0.f;
  float e[16];
#pragma unroll
  for (int k = 0; k < 16; ++k) { e[k] = expf(p[k] - m); s += e[k]; }
  float inv = 1.f / s;
#pragma unroll
  for (int k = 0; k < 16; ++k) p[k] = e[k] * inv;
}

// ---------------- MSDA: block per (b,q), thread = (h, d) ----------------
__global__ __launch_bounds__(256) void msda_kernel(
    const float* __restrict__ val, const float* __restrict__ off,
    const float* __restrict__ aw, const float* __restrict__ ref,
    const float* __restrict__ vr, float* __restrict__ outp)
{
  int bq = blockIdx.x;
  int b = bq / kQ;
  int h = threadIdx.x >> 5, d = threadIdx.x & 31;
  const int HL[4] = {80, 40, 20, 10};
  const int ST[4] = {0, 6400, 8000, 8400};
  float r0 = ref[bq * 4 + 0], r1 = ref[bq * 4 + 1];
  float r2 = ref[bq * 4 + 2], r3 = ref[bq * 4 + 3];
  const float* offrow = off + (size_t)bq * 256 + h * 32;
  const float* awrow = aw + (size_t)bq * 128 + h * 16;
  float acc = 0.f;
#pragma unroll
  for (int l = 0; l < 4; ++l) {
    int Wl = HL[l], Hl = HL[l];
    float vrx = vr[(b * 4 + l) * 2 + 0], vry = vr[(b * 4 + l) * 2 + 1];
    float cx = r0 * vrx, cy = r1 * vry;
    float sw = r2 * vrx * 0.125f, sh = r3 * vry * 0.125f;  // /P * 0.5
    const float* vbase = val + ((size_t)b * kS + ST[l]) * 256 + h * 32 + d;
#pragma unroll
    for (int p = 0; p < 4; ++p) {
      float ox = offrow[l * 8 + p * 2 + 0];
      float oy = offrow[l * 8 + p * 2 + 1];
      float x = (cx + ox * sw) * Wl - 0.5f;
      float y = (cy + oy * sh) * Hl - 0.5f;
      float x0f = floorf(x), y0f = floorf(y);
      int x0 = (int)x0f, y0 = (int)y0f;
      float fx = x - x0f, fy = y - y0f;
      float a = awrow[l * 4 + p];
#pragma unroll
      for (int dy = 0; dy < 2; ++dy) {
#pragma unroll
        for (int dx = 0; dx < 2; ++dx) {
          int xi = x0 + dx, yi = y0 + dy;
          if (xi < 0 || xi >= Wl || yi < 0 || yi >= Hl) continue;
          float w = (dx ? fx : 1.f - fx) * (dy ? fy : 1.f - fy);
          acc += a * w * vbase[(size_t)(yi * Wl + xi) * 256];
        }
      }
    }
  }
  outp[(size_t)bq * 256 + h * 32 + d] = acc;
}

// ---------------- box head final: sigmoid(bh2@W3 + b3 + inv_sigmoid(ref)) ----------------
__global__ void box_final(const float* __restrict__ bh2, const float* __restrict__ W3,
                          const float* __restrict__ b3, const float* __restrict__ ref,
                          float* __restrict__ outb)
{
  int i = blockIdx.x * 256 + threadIdx.x;
  if (i >= kBQ * 4) return;
  int rc = i >> 2, c = i & 3;
  const float* rowp = bh2 + (size_t)rc * 256;
  float acc = b3[c];
  for (int k = 0; k < 256; ++k) acc += rowp[k] * W3[k * 4 + c];
  float r = ref[i];
  r = fminf(fmaxf(r, 0.f), 1.f);
  float inv = logf(fmaxf(r, 1e-5f)) - logf(fmaxf(1.f - r, 1e-5f));
  outb[i] = 1.f / (1.f + expf(-(acc + inv)));
}

extern "C" void kernel_launch(void* const* d_in, const int* in_sizes, int n_in,
                              void* d_out, int out_size, void* d_ws, size_t ws_size,
                              hipStream_t stream)
{
  const float* target  = (const float*)d_in[0];
  const float* rpu     = (const float*)d_in[1];
  const float* memory  = (const float*)d_in[2];
  const float* vr      = (const float*)d_in[3];
  const float* sa_Wqkv = (const float*)d_in[4];
  const float* sa_bqkv = (const float*)d_in[5];
  const float* sa_Wo   = (const float*)d_in[6];
  const float* sa_bo   = (const float*)d_in[7];
  const float* ca_Woff = (const float*)d_in[8];
  const float* ca_boff = (const float*)d_in[9];
  const float* ca_Wattn= (const float*)d_in[10];
  const float* ca_battn= (const float*)d_in[11];
  const float* ca_Wv   = (const float*)d_in[12];
  const float* ca_bv   = (const float*)d_in[13];
  const float* ca_Wout = (const float*)d_in[14];
  const float* ca_bout = (const float*)d_in[15];
  const float* ffn_W1  = (const float*)d_in[16];
  const float* ffn_b1  = (const float*)d_in[17];
  const float* ffn_W2  = (const float*)d_in[18];
  const float* ffn_b2  = (const float*)d_in[19];
  const float* ln1_g   = (const float*)d_in[20];
  const float* ln1_b   = (const float*)d_in[21];
  const float* ln2_g   = (const float*)d_in[22];
  const float* ln2_b   = (const float*)d_in[23];
  const float* ln3_g   = (const float*)d_in[24];
  const float* ln3_b   = (const float*)d_in[25];
  const float* norm_g  = (const float*)d_in[26];
  const float* norm_b  = (const float*)d_in[27];
  const float* qpos_W1 = (const float*)d_in[28];
  const float* qpos_b1 = (const float*)d_in[29];
  const float* qpos_W2 = (const float*)d_in[30];
  const float* qpos_b2 = (const float*)d_in[31];
  const float* cls_W   = (const float*)d_in[32];
  const float* cls_b   = (const float*)d_in[33];
  const float* box_W1  = (const float*)d_in[34];
  const float* box_b1  = (const float*)d_in[35];
  const float* box_W2  = (const float*)d_in[36];
  const float* box_b2  = (const float*)d_in[37];
  const float* box_W3  = (const float*)d_in[38];
  const float* box_b3  = (const float*)d_in[39];

  float* ws = (float*)d_ws;
  // arena (time-aliased with val)
  float* pe     = ws;                 // 2400*512   = 1,228,800
  float* qkv    = ws + 1228800;       // 2400*768   = 1,843,200
  float* scores = ws + 3072000;       // 64*300*300 = 5,760,000
  float* qposh  = ws + 8832000;       // 2400*256   =   614,400
  float* val    = ws;                 // 68000*256  = 17,408,000
  float* P0 = ws + 17408000;
  float* output  = P0;
  float* qpos    = P0 + 614400;
  float* qbuf    = P0 + 1228800;
  float* headbuf = P0 + 1843200;
  float* tmp     = P0 + 2457600;
  float* offb    = P0 + 3072000;
  float* awb     = P0 + 3686400;
  float* ffnh    = P0 + 3993600;      // 2400*1024
  float* nob     = P0 + 6451200;
  float* bh1     = P0 + 7065600;
  float* bh2     = P0 + 7680000;
  float* ref0    = P0 + 8294400;

  hipMemcpyAsync(output, target, sizeof(float) * kBQ * kC, hipMemcpyDeviceToDevice, stream);
  sigmoid_kernel<<<(kBQ * 4 + 255) / 256, 256, 0, stream>>>(rpu, ref0, kBQ * 4);

  float* boxes_out  = (float*)d_out;                  // (L,B,Q,4)
  float* logits_out = (float*)d_out + kL * kBQ * 4;   // (L,B,Q,80)

  const float* ref = ref0;
  for (int i = 0; i < kL; ++i) {
    // positional embedding + qpos MLP
    pe_kernel<<<(kBQ * 512 + 255) / 256, 256, 0, stream>>>(ref, vr, pe);
    gemm_f32<<<dim3(4, 38), 256, 0, stream>>>(pe, qpos_W1, qpos_b1, qposh, kBQ, 256, 512, 1);
    gemm_f32<<<dim3(4, 38), 256, 0, stream>>>(qposh, qpos_W2, qpos_b2, qpos, kBQ, 256, 256, 0);
    add_kernel<<<(kBQ * kC + 255) / 256, 256, 0, stream>>>(output, qpos, qbuf, kBQ * kC);
    // self-attention
    gemm_f32<<<dim3(12, 38), 256, 0, stream>>>(qbuf, sa_Wqkv + (size_t)i * kC * 768,
                                               sa_bqkv + i * 768, qkv, kBQ, 768, 256, 0);
    attn_scores<<<dim3(10, 10, 64), 256, 0, stream>>>(qkv, scores);
    softmax_rows<<<4800, 256, 0, stream>>>(scores);
    attn_pv<<<dim3(5, 64), 256, 0, stream>>>(qkv, scores, headbuf);
    gemm_f32<<<dim3(4, 38), 256, 0, stream>>>(headbuf, sa_Wo + (size_t)i * kC * kC,
                                              sa_bo + i * kC, tmp, kBQ, 256, 256, 0);
    ln_kernel<<<kBQ, 256, 0, stream>>>(output, tmp, ln1_g + i * kC, ln1_b + i * kC, output);
    // cross-attention (MSDA)
    add_kernel<<<(kBQ * kC + 255) / 256, 256, 0, stream>>>(output, qpos, qbuf, kBQ * kC);
    gemm_f32<<<dim3(4, 38), 256, 0, stream>>>(qbuf, ca_Woff + (size_t)i * kC * 256,
                                              ca_boff + i * 256, offb, kBQ, 256, 256, 0);
    gemm_f32<<<dim3(2, 38), 256, 0, stream>>>(qbuf, ca_Wattn + (size_t)i * kC * 128,
                                              ca_battn + i * 128, awb, kBQ, 128, 256, 0);
    softmax16_kernel<<<(kBQ * kH + 255) / 256, 256, 0, stream>>>(awb);
    gemm_f32<<<dim3(4, 1063), 256, 0, stream>>>(memory, ca_Wv + (size_t)i * kC * kC,
                                                ca_bv + i * kC, val, kB * kS, 256, 256, 0);
    msda_kernel<<<kBQ, 256, 0, stream>>>(val, offb, awb, ref, vr, headbuf);
    gemm_f32<<<dim3(4, 38), 256, 0, stream>>>(headbuf, ca_Wout + (size_t)i * kC * kC,
                                              ca_bout + i * kC, tmp, kBQ, 256, 256, 0);
    ln_kernel<<<kBQ, 256, 0, stream>>>(output, tmp, ln2_g + i * kC, ln2_b + i * kC, output);
    // FFN
    gemm_f32<<<dim3(16, 38), 256, 0, stream>>>(output, ffn_W1 + (size_t)i * kC * kF,
                                               ffn_b1 + i * kF, ffnh, kBQ, kF, 256, 1);
    gemm_f32<<<dim3(4, 38), 256, 0, stream>>>(ffnh, ffn_W2 + (size_t)i * kF * kC,
                                              ffn_b2 + i * kC, tmp, kBQ, 256, kF, 0);
    ln_kernel<<<kBQ, 256, 0, stream>>>(output, tmp, ln3_g + i * kC, ln3_b + i * kC, output);
    // heads
    ln_kernel<<<kBQ, 256, 0, stream>>>(output, nullptr, norm_g, norm_b, nob);
    gemm_f32<<<dim3(4, 38), 256, 0, stream>>>(nob, box_W1 + (size_t)i * kC * kC,
                                              box_b1 + i * kC, bh1, kBQ, 256, 256, 1);
    gemm_f32<<<dim3(4, 38), 256, 0, stream>>>(bh1, box_W2 + (size_t)i * kC * kC,
                                              box_b2 + i * kC, bh2, kBQ, 256, 256, 1);
    box_final<<<(kBQ * 4 + 255) / 256, 256, 0, stream>>>(bh2, box_W3 + (size_t)i * kC * 4,
                                                         box_b3 + i * 4, ref,
                                                         boxes_out + (size_t)i * kBQ * 4);
    gemm_f32<<<dim3(2, 38), 256, 0, stream>>>(nob, cls_W + (size_t)i * kC * kNC,
                                              cls_b + i * kNC,
                                              logits_out + (size_t)i * kBQ * kNC,
                                              kBQ, kNC, 256, 0);
    ref = boxes_out + (size_t)i * kBQ * 4;
  }
}

// Round 5
// 2342.771 us; speedup vs baseline: 2.0837x; 2.0837x over previous
//
#include <hip/hip_runtime.h>

// RT-DETR decoder, round 4: resubmission of round-3 kernel (round 3 hit a
// GPU-broker acquisition timeout; no data). bf16x3 split-precision MFMA GEMMs
// (Ootomo: A=Ah+Al, B=Bh+Bl pre-split; acc = Ah*Bh + Al*Bh + Ah*Bl) for all
// small GEMMs -> ~fp32 accuracy at MFMA rate. Big val GEMM (68000x256x256)
// stays plain bf16 (error attenuated by MSDA averaging). Activations fp32.

static constexpr int kB = 8, kQ = 300, kC = 256, kH = 8, kL = 6,
                     kF = 1024, kNC = 80, kS = 8500;
static constexpr int kBQ = kB * kQ;  // 2400

typedef __attribute__((ext_vector_type(8))) short short8v;
typedef __attribute__((ext_vector_type(4))) float floatx4;

__device__ inline ushort f2bf(float f) {
  unsigned u = __float_as_uint(f);
  u += 0x7fff + ((u >> 16) & 1);
  return (ushort)(u >> 16);
}
__device__ inline float bf2f(ushort h) { return __uint_as_float((unsigned)h << 16); }

// ------- weight transpose + hi/lo split: Whi/Wlo[n][k] from W[k][n] ---------
__global__ __launch_bounds__(256) void transpose_split(
    const float* __restrict__ W, ushort* __restrict__ Whi,
    ushort* __restrict__ Wlo, int K, int N)
{
  __shared__ float t[32][33];
  size_t mat = (size_t)blockIdx.z * K * N;
  int n0 = blockIdx.x * 32, k0 = blockIdx.y * 32;
  int tx = threadIdx.x & 31, ty = threadIdx.x >> 5;  // ty 0..7
#pragma unroll
  for (int dy = 0; dy < 32; dy += 8)
    t[ty + dy][tx] = W[mat + (size_t)(k0 + ty + dy) * N + n0 + tx];
  __syncthreads();
#pragma unroll
  for (int dy = 0; dy < 32; dy += 8) {
    float v = t[tx][ty + dy];
    ushort h = f2bf(v);
    size_t o = mat + (size_t)(n0 + ty + dy) * K + k0 + tx;
    Whi[o] = h;
    Wlo[o] = f2bf(v - bf2f(h));
  }
}

// ------- bf16x3 GEMM: out = act(A@Bt^T + bias), fp32 A, split weights -------
// Tile 64x64, BK=64, 256 thr (4 waves 2x2). N%64==0, K%64==0.
__global__ __launch_bounds__(256) void gemm_x3(
    const float* __restrict__ A, const ushort* __restrict__ Bhi,
    const ushort* __restrict__ Blo, const float* __restrict__ bias,
    float* __restrict__ out, int M, int N, int K, int relu)
{
  __shared__ ushort Ah[64 * 64], Al[64 * 64], Bh[64 * 64], Bl[64 * 64];
  int tid = threadIdx.x;
  int tm = blockIdx.y * 64, tn = blockIdx.x * 64;
  int lane = tid & 63, wid = tid >> 6;
  int wr = wid >> 1, wc = wid & 1;
  int lrow = lane & 15, lk = lane >> 4;
  floatx4 acc[2][2] = {};
  for (int k0 = 0; k0 < K; k0 += 64) {
    // 512 16B-slots/tile; slot s=(row<<3)|cphys holds logical col clog=cphys^(row&7)
#pragma unroll
    for (int it = 0; it < 2; ++it) {
      int s = tid + it * 256;
      int row = s >> 3, cphys = s & 7;
      int clog = cphys ^ (row & 7);
      int gr = tm + row; if (gr > M - 1) gr = M - 1;  // clamp; epilogue masks
      const float* gp = A + (size_t)gr * K + k0 + clog * 8;
      float4 v0 = *(const float4*)gp;
      float4 v1 = *(const float4*)(gp + 4);
      float a[8] = {v0.x, v0.y, v0.z, v0.w, v1.x, v1.y, v1.z, v1.w};
      ushort h[8], l[8];
#pragma unroll
      for (int j = 0; j < 8; ++j) {
        h[j] = f2bf(a[j]);
        l[j] = f2bf(a[j] - bf2f(h[j]));
      }
      *(uint4*)&Ah[s * 8] = *(const uint4*)h;
      *(uint4*)&Al[s * 8] = *(const uint4*)l;
      size_t bo = (size_t)(tn + row) * K + k0 + clog * 8;
      *(uint4*)&Bh[s * 8] = *(const uint4*)(Bhi + bo);
      *(uint4*)&Bl[s * 8] = *(const uint4*)(Blo + bo);
    }
    __syncthreads();
#pragma unroll
    for (int ks = 0; ks < 2; ++ks) {
      short8v fah[2], fal[2], fbh[2], fbl[2];
#pragma unroll
      for (int mi = 0; mi < 2; ++mi) {
        int row = wr * 32 + mi * 16 + lrow;
        int c = ks * 4 + lk;
        int p = row * 8 + (c ^ (row & 7));
        fah[mi] = *(const short8v*)&Ah[p * 8];
        fal[mi] = *(const short8v*)&Al[p * 8];
      }
#pragma unroll
      for (int ni = 0; ni < 2; ++ni) {
        int row = wc * 32 + ni * 16 + lrow;
        int c = ks * 4 + lk;
        int p = row * 8 + (c ^ (row & 7));
        fbh[ni] = *(const short8v*)&Bh[p * 8];
        fbl[ni] = *(const short8v*)&Bl[p * 8];
      }
#pragma unroll
      for (int mi = 0; mi < 2; ++mi)
#pragma unroll
        for (int ni = 0; ni < 2; ++ni) {
          acc[mi][ni] = __builtin_amdgcn_mfma_f32_16x16x32_bf16(
              fah[mi], fbh[ni], acc[mi][ni], 0, 0, 0);
          acc[mi][ni] = __builtin_amdgcn_mfma_f32_16x16x32_bf16(
              fal[mi], fbh[ni], acc[mi][ni], 0, 0, 0);
          acc[mi][ni] = __builtin_amdgcn_mfma_f32_16x16x32_bf16(
              fah[mi], fbl[ni], acc[mi][ni], 0, 0, 0);
        }
    }
    __syncthreads();
  }
  // C/D layout: col=lane&15, row=(lane>>4)*4+j  [m89-verified]
#pragma unroll
  for (int mi = 0; mi < 2; ++mi) {
#pragma unroll
    for (int j = 0; j < 4; ++j) {
      int grow = tm + wr * 32 + mi * 16 + lk * 4 + j;
      if (grow >= M) continue;
#pragma unroll
      for (int ni = 0; ni < 2; ++ni) {
        int gcol = tn + wc * 32 + ni * 16 + lrow;
        float v = acc[mi][ni][j] + bias[gcol];
        if (relu) v = fmaxf(v, 0.f);
        out[(size_t)grow * N + gcol] = v;
      }
    }
  }
}

// ------- plain bf16 MFMA GEMM (val projection only): fp32 A -> bf16 out -----
__global__ __launch_bounds__(256) void gemm_mfma_v(
    const float* __restrict__ A, const ushort* __restrict__ Bt,
    const float* __restrict__ bias, ushort* __restrict__ outh,
    int M, int N, int K)
{
  __shared__ ushort Atile[64 * 64];
  __shared__ ushort Btile[64 * 64];
  int tid = threadIdx.x;
  int tm = blockIdx.y * 64, tn = blockIdx.x * 64;
  int lane = tid & 63, wid = tid >> 6;
  int wr = wid >> 1, wc = wid & 1;
  int lrow = lane & 15, lk = lane >> 4;
  floatx4 acc[2][2] = {};
  for (int k0 = 0; k0 < K; k0 += 64) {
#pragma unroll
    for (int it = 0; it < 2; ++it) {
      int s = tid + it * 256;
      int row = s >> 3, cphys = s & 7;
      int clog = cphys ^ (row & 7);
      int gr = tm + row; if (gr > M - 1) gr = M - 1;
      const float* gp = A + (size_t)gr * K + k0 + clog * 8;
      float4 v0 = *(const float4*)gp;
      float4 v1 = *(const float4*)(gp + 4);
      ushort* dst = &Atile[s * 8];
      dst[0] = f2bf(v0.x); dst[1] = f2bf(v0.y); dst[2] = f2bf(v0.z); dst[3] = f2bf(v0.w);
      dst[4] = f2bf(v1.x); dst[5] = f2bf(v1.y); dst[6] = f2bf(v1.z); dst[7] = f2bf(v1.w);
      const ushort* gb = Bt + (size_t)(tn + row) * K + k0 + clog * 8;
      *(uint4*)&Btile[s * 8] = *(const uint4*)gb;
    }
    __syncthreads();
#pragma unroll
    for (int ks = 0; ks < 2; ++ks) {
      short8v af[2], bfr[2];
#pragma unroll
      for (int mi = 0; mi < 2; ++mi) {
        int row = wr * 32 + mi * 16 + lrow;
        int c = ks * 4 + lk;
        int p = row * 8 + (c ^ (row & 7));
        af[mi] = *(const short8v*)&Atile[p * 8];
      }
#pragma unroll
      for (int ni = 0; ni < 2; ++ni) {
        int row = wc * 32 + ni * 16 + lrow;
        int c = ks * 4 + lk;
        int p = row * 8 + (c ^ (row & 7));
        bfr[ni] = *(const short8v*)&Btile[p * 8];
      }
#pragma unroll
      for (int mi = 0; mi < 2; ++mi)
#pragma unroll
        for (int ni = 0; ni < 2; ++ni)
          acc[mi][ni] = __builtin_amdgcn_mfma_f32_16x16x32_bf16(
              af[mi], bfr[ni], acc[mi][ni], 0, 0, 0);
    }
    __syncthreads();
  }
#pragma unroll
  for (int mi = 0; mi < 2; ++mi) {
#pragma unroll
    for (int j = 0; j < 4; ++j) {
      int grow = tm + wr * 32 + mi * 16 + lk * 4 + j;
      if (grow >= M) continue;
#pragma unroll
      for (int ni = 0; ni < 2; ++ni) {
        int gcol = tn + wc * 32 + ni * 16 + lrow;
        outh[(size_t)grow * N + gcol] = f2bf(acc[mi][ni][j] + bias[gcol]);
      }
    }
  }
}

// ---------------- fp32 GEMM (cls head, N=80) ----------------
__global__ __launch_bounds__(256) void gemm_f32(
    const float* __restrict__ A, const float* __restrict__ W,
    const float* __restrict__ bias, float* __restrict__ out,
    int M, int N, int K, int act)
{
  __shared__ float As[16][65];
  __shared__ float Ws[16][65];
  int tid = threadIdx.x;
  int tn = blockIdx.x * 64, tm = blockIdx.y * 64;
  int ty = tid >> 4, tx = tid & 15;
  float acc[4][4] = {};
  for (int k0 = 0; k0 < K; k0 += 16) {
    {
      int r = tid >> 2, kk = (tid & 3) * 4;
      int row = tm + r;
      float4 v = make_float4(0.f, 0.f, 0.f, 0.f);
      if (row < M) v = *reinterpret_cast<const float4*>(A + (size_t)row * K + k0 + kk);
      As[kk + 0][r] = v.x; As[kk + 1][r] = v.y; As[kk + 2][r] = v.z; As[kk + 3][r] = v.w;
    }
    {
      int kk = tid >> 4, c = (tid & 15) * 4;
      int col = tn + c;
      const float* wp = W + (size_t)(k0 + kk) * N + col;
      float4 v = make_float4(0.f, 0.f, 0.f, 0.f);
      if (col + 3 < N) v = *reinterpret_cast<const float4*>(wp);
      else {
        if (col + 0 < N) v.x = wp[0];
        if (col + 1 < N) v.y = wp[1];
        if (col + 2 < N) v.z = wp[2];
      }
      Ws[kk][c + 0] = v.x; Ws[kk][c + 1] = v.y; Ws[kk][c + 2] = v.z; Ws[kk][c + 3] = v.w;
    }
    __syncthreads();
#pragma unroll
    for (int k = 0; k < 16; ++k) {
      float a[4], b[4];
#pragma unroll
      for (int i = 0; i < 4; ++i) a[i] = As[k][ty * 4 + i];
#pragma unroll
      for (int j = 0; j < 4; ++j) b[j] = Ws[k][tx * 4 + j];
#pragma unroll
      for (int i = 0; i < 4; ++i)
#pragma unroll
        for (int j = 0; j < 4; ++j) acc[i][j] += a[i] * b[j];
    }
    __syncthreads();
  }
#pragma unroll
  for (int i = 0; i < 4; ++i) {
    int row = tm + ty * 4 + i;
    if (row >= M) continue;
#pragma unroll
    for (int j = 0; j < 4; ++j) {
      int col = tn + tx * 4 + j;
      if (col >= N) continue;
      float v = acc[i][j] + (bias ? bias[col] : 0.f);
      if (act) v = fmaxf(v, 0.f);
      out[(size_t)row * N + col] = v;
    }
  }
}

// ---------------- LayerNorm: out = LN(x + delta) * g + b ----------------
__global__ __launch_bounds__(256) void ln_kernel(
    const float* __restrict__ x, const float* __restrict__ delta,
    const float* __restrict__ g, const float* __restrict__ b,
    float* __restrict__ out)
{
  __shared__ float red[4];
  int row = blockIdx.x, t = threadIdx.x;
  size_t idx = (size_t)row * 256 + t;
  float v = x[idx] + (delta ? delta[idx] : 0.f);
  float s = v;
#pragma unroll
  for (int o = 32; o; o >>= 1) s += __shfl_xor(s, o);
  if ((t & 63) == 0) red[t >> 6] = s;
  __syncthreads();
  float mean = (red[0] + red[1] + red[2] + red[3]) * (1.f / 256.f);
  __syncthreads();
  float dv = v - mean;
  float s2 = dv * dv;
#pragma unroll
  for (int o = 32; o; o >>= 1) s2 += __shfl_xor(s2, o);
  if ((t & 63) == 0) red[t >> 6] = s2;
  __syncthreads();
  float var = (red[0] + red[1] + red[2] + red[3]) * (1.f / 256.f);
  out[idx] = dv * rsqrtf(var + 1e-5f) * g[t] + b[t];
}

__global__ void add_kernel(const float* __restrict__ a, const float* __restrict__ b,
                           float* __restrict__ o, int n)
{
  int i = blockIdx.x * 256 + threadIdx.x;
  if (i < n) o[i] = a[i] + b[i];
}

__global__ void sigmoid_kernel(const float* __restrict__ x, float* __restrict__ o, int n)
{
  int i = blockIdx.x * 256 + threadIdx.x;
  if (i < n) o[i] = 1.f / (1.f + expf(-x[i]));
}

// ---------------- sine positional embedding (B,Q,512) fp32 ----------------
__global__ void pe_kernel(const float* __restrict__ ref, const float* __restrict__ vr,
                          float* __restrict__ pe)
{
  int idx = blockIdx.x * 256 + threadIdx.x;
  if (idx >= kBQ * 512) return;
  int ch = idx & 511, bq = idx >> 9;
  int b = bq / kQ;
  int c = ch >> 7, j = ch & 127, p = j >> 1;
  float pos = ref[bq * 4 + c] * vr[(b * 4 + 0) * 2 + (c & 1)];
  float dim = expf((float)p * (9.210340371976184f / 64.f));  // 10000^(p/64)
  float arg = pos * 6.283185307179586f / dim;
  pe[idx] = (j & 1) ? cosf(arg) : sinf(arg);
}

// ---------------- MHA ----------------
__global__ __launch_bounds__(256) void attn_scores(const float* __restrict__ qkv,
                                                   float* __restrict__ sc)
{
  int bh = blockIdx.z;
  int b = bh >> 3, h = bh & 7;
  int qt = blockIdx.y * 32, kt = blockIdx.x * 32;
  __shared__ float qs[32][33], ks[32][33];
  int r = threadIdx.x >> 3, dd = (threadIdx.x & 7) * 4;
  {
    int qi = qt + r;
    float4 v = make_float4(0.f, 0.f, 0.f, 0.f);
    if (qi < kQ) v = *reinterpret_cast<const float4*>(qkv + (size_t)(b * kQ + qi) * 768 + h * 32 + dd);
    qs[r][dd] = v.x; qs[r][dd + 1] = v.y; qs[r][dd + 2] = v.z; qs[r][dd + 3] = v.w;
    int kj = kt + r;
    float4 w = make_float4(0.f, 0.f, 0.f, 0.f);
    if (kj < kQ) w = *reinterpret_cast<const float4*>(qkv + (size_t)(b * kQ + kj) * 768 + 256 + h * 32 + dd);
    ks[r][dd] = w.x; ks[r][dd + 1] = w.y; ks[r][dd + 2] = w.z; ks[r][dd + 3] = w.w;
  }
  __syncthreads();
  int ty = (threadIdx.x >> 4) * 2, tx = (threadIdx.x & 15) * 2;
  float acc[2][2] = {};
#pragma unroll
  for (int k = 0; k < 32; ++k) {
    float a0 = qs[ty][k], a1 = qs[ty + 1][k];
    float b0 = ks[tx][k], b1 = ks[tx + 1][k];
    acc[0][0] += a0 * b0; acc[0][1] += a0 * b1;
    acc[1][0] += a1 * b0; acc[1][1] += a1 * b1;
  }
  const float scale = 0.17677669529663687f;  // 1/sqrt(32)
#pragma unroll
  for (int i = 0; i < 2; ++i) {
    int qi = qt + ty + i;
    if (qi >= kQ) continue;
#pragma unroll
    for (int j = 0; j < 2; ++j) {
      int kj = kt + tx + j;
      if (kj >= kQ) continue;
      sc[((size_t)bh * kQ + qi) * kQ + kj] = acc[i][j] * scale;
    }
  }
}

__global__ __launch_bounds__(256) void softmax_rows(float* __restrict__ sc)
{
  int wid = blockIdx.x * 4 + (threadIdx.x >> 6);
  int lane = threadIdx.x & 63;
  float* row = sc + (size_t)wid * kQ;
  float v[5];
  float m = -1e30f;
#pragma unroll
  for (int i = 0; i < 5; ++i) {
    int idx = lane + i * 64;
    v[i] = (idx < kQ) ? row[idx] : -1e30f;
    m = fmaxf(m, v[i]);
  }
#pragma unroll
  for (int o = 32; o; o >>= 1) m = fmaxf(m, __shfl_xor(m, o));
  float s = 0.f;
#pragma unroll
  for (int i = 0; i < 5; ++i) { v[i] = expf(v[i] - m); s += v[i]; }
#pragma unroll
  for (int o = 32; o; o >>= 1) s += __shfl_xor(s, o);
  float inv = 1.f / s;
#pragma unroll
  for (int i = 0; i < 5; ++i) {
    int idx = lane + i * 64;
    if (idx < kQ) row[idx] = v[i] * inv;
  }
}

__global__ __launch_bounds__(256) void attn_pv(const float* __restrict__ qkv,
                                               const float* __restrict__ att,
                                               float* __restrict__ outp)
{
  int bh = blockIdx.y;
  int b = bh >> 3, h = bh & 7;
  __shared__ float vs[300][32];
  int d = threadIdx.x & 31;
  for (int k = threadIdx.x >> 5; k < kQ; k += 8)
    vs[k][d] = qkv[(size_t)(b * kQ + k) * 768 + 512 + h * 32 + d];
  __syncthreads();
  int qr = threadIdx.x >> 5;
  int qend = (kQ < (int)(blockIdx.x * 64 + 64)) ? kQ : (int)(blockIdx.x * 64 + 64);
  for (int q = blockIdx.x * 64 + qr; q < qend; q += 8) {
    const float* arow = att + ((size_t)bh * kQ + q) * kQ;
    float acc = 0.f;
    for (int k = 0; k < kQ; ++k) acc += arow[k] * vs[k][d];
    outp[(size_t)(b * kQ + q) * 256 + h * 32 + d] = acc;
  }
}

__global__ void softmax16_kernel(float* __restrict__ x)
{
  int r = blockIdx.x * 256 + threadIdx.x;
  if (r >= kBQ * kH) return;
  float* p = x + (size_t)r * 16;
  float m = -1e30f;
#pragma unroll
  for (int k = 0; k < 16; ++k) m = fmaxf(m, p[k]);
  float s = 0.f;
  float e[16];
#pragma unroll
  for (int k = 0; k < 16; ++k) { e[k] = expf(p[k] - m); s += e[k]; }
  float inv = 1.f / s;
#pragma unroll
  for (int k = 0; k < 16; ++k) p[k] = e[k] * inv;
}

// ---------------- MSDA: val bf16 -> fp32 out ----------------
__global__ __launch_bounds__(256) void msda_kernel(
    const ushort* __restrict__ val, const float* __restrict__ off,
    const float* __restrict__ aw, const float* __restrict__ ref,
    const float* __restrict__ vr, float* __restrict__ outp)
{
  int bq = blockIdx.x;
  int b = bq / kQ;
  int h = threadIdx.x >> 5, d = threadIdx.x & 31;
  const int HL[4] = {80, 40, 20, 10};
  const int ST[4] = {0, 6400, 8000, 8400};
  float r0 = ref[bq * 4 + 0], r1 = ref[bq * 4 + 1];
  float r2 = ref[bq * 4 + 2], r3 = ref[bq * 4 + 3];
  const float* offrow = off + (size_t)bq * 256 + h * 32;
  const float* awrow = aw + (size_t)bq * 128 + h * 16;
  float acc = 0.f;
#pragma unroll
  for (int l = 0; l < 4; ++l) {
    int Wl = HL[l], Hl = HL[l];
    float vrx = vr[(b * 4 + l) * 2 + 0], vry = vr[(b * 4 + l) * 2 + 1];
    float cx = r0 * vrx, cy = r1 * vry;
    float sw = r2 * vrx * 0.125f, sh = r3 * vry * 0.125f;
    const ushort* vbase = val + ((size_t)b * kS + ST[l]) * 256 + h * 32 + d;
#pragma unroll
    for (int p = 0; p < 4; ++p) {
      float ox = offrow[l * 8 + p * 2 + 0];
      float oy = offrow[l * 8 + p * 2 + 1];
      float x = (cx + ox * sw) * Wl - 0.5f;
      float y = (cy + oy * sh) * Hl - 0.5f;
      float x0f = floorf(x), y0f = floorf(y);
      int x0 = (int)x0f, y0 = (int)y0f;
      float fx = x - x0f, fy = y - y0f;
      float a = awrow[l * 4 + p];
#pragma unroll
      for (int dy = 0; dy < 2; ++dy) {
#pragma unroll
        for (int dx = 0; dx < 2; ++dx) {
          int xi = x0 + dx, yi = y0 + dy;
          if (xi < 0 || xi >= Wl || yi < 0 || yi >= Hl) continue;
          float w = (dx ? fx : 1.f - fx) * (dy ? fy : 1.f - fy);
          acc += a * w * bf2f(vbase[(size_t)(yi * Wl + xi) * 256]);
        }
      }
    }
  }
  outp[(size_t)bq * 256 + h * 32 + d] = acc;
}

// ---------------- box head final ----------------
__global__ void box_final(const float* __restrict__ bh2, const float* __restrict__ W3,
                          const float* __restrict__ b3, const float* __restrict__ ref,
                          float* __restrict__ outb)
{
  int i = blockIdx.x * 256 + threadIdx.x;
  if (i >= kBQ * 4) return;
  int rc = i >> 2, c = i & 3;
  const float* rowp = bh2 + (size_t)rc * 256;
  float acc = b3[c];
  for (int k = 0; k < 256; ++k) acc += rowp[k] * W3[k * 4 + c];
  float r = ref[i];
  r = fminf(fmaxf(r, 0.f), 1.f);
  float inv = logf(fmaxf(r, 1e-5f)) - logf(fmaxf(1.f - r, 1e-5f));
  outb[i] = 1.f / (1.f + expf(-(acc + inv)));
}

extern "C" void kernel_launch(void* const* d_in, const int* in_sizes, int n_in,
                              void* d_out, int out_size, void* d_ws, size_t ws_size,
                              hipStream_t stream)
{
  const float* target  = (const float*)d_in[0];
  const float* rpu     = (const float*)d_in[1];
  const float* memory  = (const float*)d_in[2];
  const float* vr      = (const float*)d_in[3];
  const float* sa_Wqkv = (const float*)d_in[4];
  const float* sa_bqkv = (const float*)d_in[5];
  const float* sa_Wo   = (const float*)d_in[6];
  const float* sa_bo   = (const float*)d_in[7];
  const float* ca_Woff = (const float*)d_in[8];
  const float* ca_boff = (const float*)d_in[9];
  const float* ca_Wattn= (const float*)d_in[10];
  const float* ca_battn= (const float*)d_in[11];
  const float* ca_Wv   = (const float*)d_in[12];
  const float* ca_bv   = (const float*)d_in[13];
  const float* ca_Wout = (const float*)d_in[14];
  const float* ca_bout = (const float*)d_in[15];
  const float* ffn_W1  = (const float*)d_in[16];
  const float* ffn_b1  = (const float*)d_in[17];
  const float* ffn_W2  = (const float*)d_in[18];
  const float* ffn_b2  = (const float*)d_in[19];
  const float* ln1_g   = (const float*)d_in[20];
  const float* ln1_b   = (const float*)d_in[21];
  const float* ln2_g   = (const float*)d_in[22];
  const float* ln2_b   = (const float*)d_in[23];
  const float* ln3_g   = (const float*)d_in[24];
  const float* ln3_b   = (const float*)d_in[25];
  const float* norm_g  = (const float*)d_in[26];
  const float* norm_b  = (const float*)d_in[27];
  const float* qpos_W1 = (const float*)d_in[28];
  const float* qpos_b1 = (const float*)d_in[29];
  const float* qpos_W2 = (const float*)d_in[30];
  const float* qpos_b2 = (const float*)d_in[31];
  const float* cls_W   = (const float*)d_in[32];
  const float* cls_b   = (const float*)d_in[33];
  const float* box_W1  = (const float*)d_in[34];
  const float* box_b1  = (const float*)d_in[35];
  const float* box_W2  = (const float*)d_in[36];
  const float* box_b2  = (const float*)d_in[37];
  const float* box_W3  = (const float*)d_in[38];
  const float* box_b3  = (const float*)d_in[39];

  char* wsb = (char*)d_ws;
  // ---- arena [0, 37,785,600) : fp32 pe/qkv/scores/qposh, aliased with val_bf
  float*  pe     = (float*) (wsb + 0);          // 2400*512 f32  = 4,915,200 B
  float*  qkv    = (float*) (wsb + 4915200);    // 2400*768 f32  = 7,372,800 B
  float*  scores = (float*) (wsb + 12288000);   // 64*300*300 f32= 23,040,000 B
  float*  qposh  = (float*) (wsb + 35328000);   // 2400*256 f32  = 2,457,600 B
  ushort* val_bf = (ushort*)(wsb + 0);          // 68000*256 bf16= 34,816,000 B
  // ---- persistent fp32 buffers (each 2,457,600 B unless noted) ----
  size_t P = 37785600;
  float*  output = (float*)(wsb + P);
  float*  qpos   = (float*)(wsb + P + 2457600);
  float*  qbuf   = (float*)(wsb + P + 4915200);   // alias bh1
  float*  head   = (float*)(wsb + P + 7372800);
  float*  tmp    = (float*)(wsb + P + 9830400);   // alias bh2
  float*  offb   = (float*)(wsb + P + 12288000);  // alias nob
  float*  awb    = (float*)(wsb + P + 14745600);  // 1,228,800 B
  float*  ffnh   = (float*)(wsb + P + 15974400);  // 9,830,400 B
  float*  ref0   = (float*)(wsb + P + 25804800);  // 38,400 B
  float*  bh1 = qbuf;
  float*  bh2 = tmp;
  float*  nob = offb;
  // ---- split weights: hi set then lo set (7,077,888 ushorts each) ----
  ushort* wHI = (ushort*)(wsb + P + 25843200);
  ushort* wLO = wHI + 7077888;

  ushort* wq_h    = wHI + 0,       *wq_l    = wLO + 0;        // (L,768,256)
  ushort* wo_h    = wHI + 1179648, *wo_l    = wLO + 1179648;  // (L,256,256)
  ushort* woff_h  = wHI + 1572864, *woff_l  = wLO + 1572864;  // (L,256,256)
  ushort* wattn_h = wHI + 1966080, *wattn_l = wLO + 1966080;  // (L,128,256)
  ushort* wv_h    = wHI + 2162688, *wv_l    = wLO + 2162688;  // (L,256,256)
  ushort* wout_h  = wHI + 2555904, *wout_l  = wLO + 2555904;  // (L,256,256)
  ushort* w1_h    = wHI + 2949120, *w1_l    = wLO + 2949120;  // (L,1024,256)
  ushort* w2_h    = wHI + 4521984, *w2_l    = wLO + 4521984;  // (L,256,1024)
  ushort* wq1_h   = wHI + 6094848, *wq1_l   = wLO + 6094848;  // (256,512)
  ushort* wq2_h   = wHI + 6225920, *wq2_l   = wLO + 6225920;  // (256,256)
  ushort* wb1_h   = wHI + 6291456, *wb1_l   = wLO + 6291456;  // (L,256,256)
  ushort* wb2_h   = wHI + 6684672, *wb2_l   = wLO + 6684672;  // (L,256,256)

  // ---- once per launch: transpose + hi/lo split ----
  transpose_split<<<dim3(24, 8, 6), 256, 0, stream>>>(sa_Wqkv, wq_h, wq_l, 256, 768);
  transpose_split<<<dim3(8, 8, 6), 256, 0, stream>>>(sa_Wo, wo_h, wo_l, 256, 256);
  transpose_split<<<dim3(8, 8, 6), 256, 0, stream>>>(ca_Woff, woff_h, woff_l, 256, 256);
  transpose_split<<<dim3(4, 8, 6), 256, 0, stream>>>(ca_Wattn, wattn_h, wattn_l, 256, 128);
  transpose_split<<<dim3(8, 8, 6), 256, 0, stream>>>(ca_Wv, wv_h, wv_l, 256, 256);
  transpose_split<<<dim3(8, 8, 6), 256, 0, stream>>>(ca_Wout, wout_h, wout_l, 256, 256);
  transpose_split<<<dim3(32, 8, 6), 256, 0, stream>>>(ffn_W1, w1_h, w1_l, 256, 1024);
  transpose_split<<<dim3(8, 32, 6), 256, 0, stream>>>(ffn_W2, w2_h, w2_l, 1024, 256);
  transpose_split<<<dim3(8, 16, 1), 256, 0, stream>>>(qpos_W1, wq1_h, wq1_l, 512, 256);
  transpose_split<<<dim3(8, 8, 1), 256, 0, stream>>>(qpos_W2, wq2_h, wq2_l, 256, 256);
  transpose_split<<<dim3(8, 8, 6), 256, 0, stream>>>(box_W1, wb1_h, wb1_l, 256, 256);
  transpose_split<<<dim3(8, 8, 6), 256, 0, stream>>>(box_W2, wb2_h, wb2_l, 256, 256);

  hipMemcpyAsync(output, target, sizeof(float) * kBQ * kC, hipMemcpyDeviceToDevice, stream);
  sigmoid_kernel<<<(kBQ * 4 + 255) / 256, 256, 0, stream>>>(rpu, ref0, kBQ * 4);

  float* boxes_out  = (float*)d_out;                  // (L,B,Q,4)
  float* logits_out = (float*)d_out + kL * kBQ * 4;   // (L,B,Q,80)

  const float* ref = ref0;
  for (int i = 0; i < kL; ++i) {
    // positional embedding + qpos MLP
    pe_kernel<<<(kBQ * 512 + 255) / 256, 256, 0, stream>>>(ref, vr, pe);
    gemm_x3<<<dim3(4, 38), 256, 0, stream>>>(pe, wq1_h, wq1_l, qpos_b1,
                                             qposh, kBQ, 256, 512, 1);
    gemm_x3<<<dim3(4, 38), 256, 0, stream>>>(qposh, wq2_h, wq2_l, qpos_b2,
                                             qpos, kBQ, 256, 256, 0);
    add_kernel<<<(kBQ * kC + 255) / 256, 256, 0, stream>>>(output, qpos, qbuf, kBQ * kC);
    // self-attention
    gemm_x3<<<dim3(12, 38), 256, 0, stream>>>(qbuf, wq_h + (size_t)i * 196608,
                                              wq_l + (size_t)i * 196608,
                                              sa_bqkv + i * 768, qkv, kBQ, 768, 256, 0);
    attn_scores<<<dim3(10, 10, 64), 256, 0, stream>>>(qkv, scores);
    softmax_rows<<<4800, 256, 0, stream>>>(scores);
    attn_pv<<<dim3(5, 64), 256, 0, stream>>>(qkv, scores, head);
    gemm_x3<<<dim3(4, 38), 256, 0, stream>>>(head, wo_h + (size_t)i * 65536,
                                             wo_l + (size_t)i * 65536,
                                             sa_bo + i * kC, tmp, kBQ, 256, 256, 0);
    ln_kernel<<<kBQ, 256, 0, stream>>>(output, tmp, ln1_g + i * kC, ln1_b + i * kC, output);
    // cross-attention (MSDA)
    add_kernel<<<(kBQ * kC + 255) / 256, 256, 0, stream>>>(output, qpos, qbuf, kBQ * kC);
    gemm_x3<<<dim3(4, 38), 256, 0, stream>>>(qbuf, woff_h + (size_t)i * 65536,
                                             woff_l + (size_t)i * 65536,
                                             ca_boff + i * 256, offb, kBQ, 256, 256, 0);
    gemm_x3<<<dim3(2, 38), 256, 0, stream>>>(qbuf, wattn_h + (size_t)i * 32768,
                                             wattn_l + (size_t)i * 32768,
                                             ca_battn + i * 128, awb, kBQ, 128, 256, 0);
    softmax16_kernel<<<(kBQ * kH + 255) / 256, 256, 0, stream>>>(awb);
    gemm_mfma_v<<<dim3(4, 1063), 256, 0, stream>>>(memory, wv_h + (size_t)i * 65536,
                                                   ca_bv + i * kC, val_bf, kB * kS, 256, 256);
    msda_kernel<<<kBQ, 256, 0, stream>>>(val_bf, offb, awb, ref, vr, head);
    gemm_x3<<<dim3(4, 38), 256, 0, stream>>>(head, wout_h + (size_t)i * 65536,
                                             wout_l + (size_t)i * 65536,
                                             ca_bout + i * kC, tmp, kBQ, 256, 256, 0);
    ln_kernel<<<kBQ, 256, 0, stream>>>(output, tmp, ln2_g + i * kC, ln2_b + i * kC, output);
    // FFN
    gemm_x3<<<dim3(16, 38), 256, 0, stream>>>(output, w1_h + (size_t)i * 262144,
                                              w1_l + (size_t)i * 262144,
                                              ffn_b1 + i * kF, ffnh, kBQ, kF, 256, 1);
    gemm_x3<<<dim3(4, 38), 256, 0, stream>>>(ffnh, w2_h + (size_t)i * 262144,
                                             w2_l + (size_t)i * 262144,
                                             ffn_b2 + i * kC, tmp, kBQ, 256, kF, 0);
    ln_kernel<<<kBQ, 256, 0, stream>>>(output, tmp, ln3_g + i * kC, ln3_b + i * kC, output);
    // heads
    ln_kernel<<<kBQ, 256, 0, stream>>>(output, nullptr, norm_g, norm_b, nob);
    gemm_x3<<<dim3(4, 38), 256, 0, stream>>>(nob, wb1_h + (size_t)i * 65536,
                                             wb1_l + (size_t)i * 65536,
                                             box_b1 + i * kC, bh1, kBQ, 256, 256, 1);
    gemm_x3<<<dim3(4, 38), 256, 0, stream>>>(bh1, wb2_h + (size_t)i * 65536,
                                             wb2_l + (size_t)i * 65536,
                                             box_b2 + i * kC, bh2, kBQ, 256, 256, 1);
    box_final<<<(kBQ * 4 + 255) / 256, 256, 0, stream>>>(bh2, box_W3 + (size_t)i * kC * 4,
                                                         box_b3 + i * 4, ref,
                                                         boxes_out + (size_t)i * kBQ * 4);
    gemm_f32<<<dim3(2, 38), 256, 0, stream>>>(nob, cls_W + (size_t)i * kC * kNC,
                                              cls_b + i * kNC,
                                              logits_out + (size_t)i * kBQ * kNC,
                                              kBQ, kNC, 256, 0);
    ref = boxes_out + (size_t)i * kBQ * 4;
  }
}

// Round 6
// 2187.826 us; speedup vs baseline: 2.2313x; 1.0708x over previous
//
#include <hip/hip_runtime.h>

// RT-DETR decoder, round 5. Changes vs round 3 (measured: val GEMM HBM-bound,
// FETCH 136MB vs 70MB ideal from 4x A re-read across column tiles):
//  1. gemm_val: full-N 64x256 tile -> A read exactly once per layer; B (128KB)
//     L2-resident. Plain bf16 (precision unchanged).
//  2. gemm_x3 gains A2 (fused residual add in staging) + padded-N support;
//     removes 2 add dispatches/layer; cls head now x3 (N padded 80->128).
//  3. Everything else unchanged (attention/msda unprofiled -> next round).

static constexpr int kB = 8, kQ = 300, kC = 256, kH = 8, kL = 6,
                     kF = 1024, kNC = 80, kS = 8500;
static constexpr int kBQ = kB * kQ;  // 2400

typedef __attribute__((ext_vector_type(8))) short short8v;
typedef __attribute__((ext_vector_type(4))) float floatx4;

__device__ inline ushort f2bf(float f) {
  unsigned u = __float_as_uint(f);
  u += 0x7fff + ((u >> 16) & 1);
  return (ushort)(u >> 16);
}
__device__ inline float bf2f(ushort h) { return __uint_as_float((unsigned)h << 16); }

// ------- weight transpose + hi/lo split (+N padding): Wt[n][k] ---------------
__global__ __launch_bounds__(256) void transpose_split_pad(
    const float* __restrict__ W, ushort* __restrict__ Whi,
    ushort* __restrict__ Wlo, int K, int N, int Npad)
{
  __shared__ float t[32][33];
  size_t matI = (size_t)blockIdx.z * K * N;
  size_t matO = (size_t)blockIdx.z * K * Npad;
  int n0 = blockIdx.x * 32, k0 = blockIdx.y * 32;
  int tx = threadIdx.x & 31, ty = threadIdx.x >> 5;  // ty 0..7
#pragma unroll
  for (int dy = 0; dy < 32; dy += 8) {
    int n = n0 + tx;
    t[ty + dy][tx] = (n < N) ? W[matI + (size_t)(k0 + ty + dy) * N + n] : 0.f;
  }
  __syncthreads();
#pragma unroll
  for (int dy = 0; dy < 32; dy += 8) {
    float v = t[tx][ty + dy];
    ushort h = f2bf(v);
    size_t o = matO + (size_t)(n0 + ty + dy) * K + k0 + tx;
    Whi[o] = h;
    Wlo[o] = f2bf(v - bf2f(h));
  }
}

// ------- bf16x3 GEMM: out = act((A[+A2])@Bt^T + bias) ------------------------
// A,A2 fp32 MxK; Bhi/Blo: Npad x K bf16. Tile 64x64, BK=64, 256 thr.
__global__ __launch_bounds__(256) void gemm_x3(
    const float* __restrict__ A, const float* __restrict__ A2,
    const ushort* __restrict__ Bhi, const ushort* __restrict__ Blo,
    const float* __restrict__ bias, float* __restrict__ out,
    int M, int N, int Nout, int K, int relu)
{
  __shared__ ushort Ah[64 * 64], Al[64 * 64], Bh[64 * 64], Bl[64 * 64];
  int tid = threadIdx.x;
  int tm = blockIdx.y * 64, tn = blockIdx.x * 64;
  int lane = tid & 63, wid = tid >> 6;
  int wr = wid >> 1, wc = wid & 1;
  int lrow = lane & 15, lk = lane >> 4;
  floatx4 acc[2][2] = {};
  for (int k0 = 0; k0 < K; k0 += 64) {
    // 512 16B-slots/tile; slot s=(row<<3)|cphys holds logical col clog=cphys^(row&7)
#pragma unroll
    for (int it = 0; it < 2; ++it) {
      int s = tid + it * 256;
      int row = s >> 3, cphys = s & 7;
      int clog = cphys ^ (row & 7);
      int gr = tm + row; if (gr > M - 1) gr = M - 1;  // clamp; epilogue masks
      const float* gp = A + (size_t)gr * K + k0 + clog * 8;
      float4 v0 = *(const float4*)gp;
      float4 v1 = *(const float4*)(gp + 4);
      float a[8] = {v0.x, v0.y, v0.z, v0.w, v1.x, v1.y, v1.z, v1.w};
      if (A2) {
        const float* gp2 = A2 + (size_t)gr * K + k0 + clog * 8;
        float4 w0 = *(const float4*)gp2;
        float4 w1 = *(const float4*)(gp2 + 4);
        a[0] += w0.x; a[1] += w0.y; a[2] += w0.z; a[3] += w0.w;
        a[4] += w1.x; a[5] += w1.y; a[6] += w1.z; a[7] += w1.w;
      }
      ushort h[8], l[8];
#pragma unroll
      for (int j = 0; j < 8; ++j) {
        h[j] = f2bf(a[j]);
        l[j] = f2bf(a[j] - bf2f(h[j]));
      }
      *(uint4*)&Ah[s * 8] = *(const uint4*)h;
      *(uint4*)&Al[s * 8] = *(const uint4*)l;
      size_t bo = (size_t)(tn + row) * K + k0 + clog * 8;
      *(uint4*)&Bh[s * 8] = *(const uint4*)(Bhi + bo);
      *(uint4*)&Bl[s * 8] = *(const uint4*)(Blo + bo);
    }
    __syncthreads();
#pragma unroll
    for (int ks = 0; ks < 2; ++ks) {
      short8v fah[2], fal[2], fbh[2], fbl[2];
#pragma unroll
      for (int mi = 0; mi < 2; ++mi) {
        int row = wr * 32 + mi * 16 + lrow;
        int c = ks * 4 + lk;
        int p = row * 8 + (c ^ (row & 7));
        fah[mi] = *(const short8v*)&Ah[p * 8];
        fal[mi] = *(const short8v*)&Al[p * 8];
      }
#pragma unroll
      for (int ni = 0; ni < 2; ++ni) {
        int row = wc * 32 + ni * 16 + lrow;
        int c = ks * 4 + lk;
        int p = row * 8 + (c ^ (row & 7));
        fbh[ni] = *(const short8v*)&Bh[p * 8];
        fbl[ni] = *(const short8v*)&Bl[p * 8];
      }
#pragma unroll
      for (int mi = 0; mi < 2; ++mi)
#pragma unroll
        for (int ni = 0; ni < 2; ++ni) {
          acc[mi][ni] = __builtin_amdgcn_mfma_f32_16x16x32_bf16(
              fah[mi], fbh[ni], acc[mi][ni], 0, 0, 0);
          acc[mi][ni] = __builtin_amdgcn_mfma_f32_16x16x32_bf16(
              fal[mi], fbh[ni], acc[mi][ni], 0, 0, 0);
          acc[mi][ni] = __builtin_amdgcn_mfma_f32_16x16x32_bf16(
              fah[mi], fbl[ni], acc[mi][ni], 0, 0, 0);
        }
    }
    __syncthreads();
  }
  // C/D layout: col=lane&15, row=(lane>>4)*4+j
#pragma unroll
  for (int mi = 0; mi < 2; ++mi) {
#pragma unroll
    for (int j = 0; j < 4; ++j) {
      int grow = tm + wr * 32 + mi * 16 + lk * 4 + j;
      if (grow >= M) continue;
#pragma unroll
      for (int ni = 0; ni < 2; ++ni) {
        int gcol = tn + wc * 32 + ni * 16 + lrow;
        if (gcol >= Nout) continue;
        float v = acc[mi][ni][j] + bias[gcol];
        if (relu) v = fmaxf(v, 0.f);
        out[(size_t)grow * Nout + gcol] = v;
      }
    }
  }
}

// ------- val GEMM: full-N tile 64x256, plain bf16, A read once ---------------
__global__ __launch_bounds__(256) void gemm_val(
    const float* __restrict__ A, const ushort* __restrict__ Bt,
    const float* __restrict__ bias, ushort* __restrict__ outh, int M)
{
  __shared__ ushort At[64 * 64];
  __shared__ ushort Bs[256 * 64];
  int tid = threadIdx.x;
  int tm = blockIdx.x * 64;
  int lane = tid & 63, wid = tid >> 6;
  int lrow = lane & 15, lk = lane >> 4;
  floatx4 acc[16] = {};
  for (int k0 = 0; k0 < 256; k0 += 64) {
#pragma unroll
    for (int it = 0; it < 2; ++it) {
      int s = tid + it * 256;
      int row = s >> 3, cphys = s & 7, clog = cphys ^ (row & 7);
      int gr = tm + row; if (gr > M - 1) gr = M - 1;
      const float* gp = A + (size_t)gr * 256 + k0 + clog * 8;
      float4 v0 = *(const float4*)gp;
      float4 v1 = *(const float4*)(gp + 4);
      ushort* dst = &At[s * 8];
      dst[0] = f2bf(v0.x); dst[1] = f2bf(v0.y); dst[2] = f2bf(v0.z); dst[3] = f2bf(v0.w);
      dst[4] = f2bf(v1.x); dst[5] = f2bf(v1.y); dst[6] = f2bf(v1.z); dst[7] = f2bf(v1.w);
    }
#pragma unroll
    for (int it = 0; it < 8; ++it) {
      int s = tid + it * 256;
      int row = s >> 3, cphys = s & 7, clog = cphys ^ (row & 7);
      *(uint4*)&Bs[s * 8] = *(const uint4*)(Bt + (size_t)row * 256 + k0 + clog * 8);
    }
    __syncthreads();
#pragma unroll
    for (int ks = 0; ks < 2; ++ks) {
      int c = ks * 4 + lk;
      int arow = wid * 16 + lrow;
      short8v af = *(const short8v*)&At[(arow * 8 + (c ^ (arow & 7))) * 8];
#pragma unroll
      for (int nf = 0; nf < 16; ++nf) {
        int brow = nf * 16 + lrow;
        short8v bf = *(const short8v*)&Bs[(brow * 8 + (c ^ (brow & 7))) * 8];
        acc[nf] = __builtin_amdgcn_mfma_f32_16x16x32_bf16(af, bf, acc[nf], 0, 0, 0);
      }
    }
    __syncthreads();
  }
#pragma unroll
  for (int j = 0; j < 4; ++j) {
    int grow = tm + wid * 16 + lk * 4 + j;
    if (grow >= M) continue;
#pragma unroll
    for (int nf = 0; nf < 16; ++nf) {
      int gcol = nf * 16 + lrow;
      outh[(size_t)grow * 256 + gcol] = f2bf(acc[nf][j] + bias[gcol]);
    }
  }
}

// ---------------- LayerNorm: out = LN(x + delta) * g + b ----------------
__global__ __launch_bounds__(256) void ln_kernel(
    const float* __restrict__ x, const float* __restrict__ delta,
    const float* __restrict__ g, const float* __restrict__ b,
    float* __restrict__ out)
{
  __shared__ float red[4];
  int row = blockIdx.x, t = threadIdx.x;
  size_t idx = (size_t)row * 256 + t;
  float v = x[idx] + (delta ? delta[idx] : 0.f);
  float s = v;
#pragma unroll
  for (int o = 32; o; o >>= 1) s += __shfl_xor(s, o);
  if ((t & 63) == 0) red[t >> 6] = s;
  __syncthreads();
  float mean = (red[0] + red[1] + red[2] + red[3]) * (1.f / 256.f);
  __syncthreads();
  float dv = v - mean;
  float s2 = dv * dv;
#pragma unroll
  for (int o = 32; o; o >>= 1) s2 += __shfl_xor(s2, o);
  if ((t & 63) == 0) red[t >> 6] = s2;
  __syncthreads();
  float var = (red[0] + red[1] + red[2] + red[3]) * (1.f / 256.f);
  out[idx] = dv * rsqrtf(var + 1e-5f) * g[t] + b[t];
}

__global__ void sigmoid_kernel(const float* __restrict__ x, float* __restrict__ o, int n)
{
  int i = blockIdx.x * 256 + threadIdx.x;
  if (i < n) o[i] = 1.f / (1.f + expf(-x[i]));
}

// ---------------- sine positional embedding (B,Q,512) fp32 ----------------
__global__ void pe_kernel(const float* __restrict__ ref, const float* __restrict__ vr,
                          float* __restrict__ pe)
{
  int idx = blockIdx.x * 256 + threadIdx.x;
  if (idx >= kBQ * 512) return;
  int ch = idx & 511, bq = idx >> 9;
  int b = bq / kQ;
  int c = ch >> 7, j = ch & 127, p = j >> 1;
  float pos = ref[bq * 4 + c] * vr[(b * 4 + 0) * 2 + (c & 1)];
  float dim = expf((float)p * (9.210340371976184f / 64.f));  // 10000^(p/64)
  float arg = pos * 6.283185307179586f / dim;
  pe[idx] = (j & 1) ? cosf(arg) : sinf(arg);
}

// ---------------- MHA ----------------
__global__ __launch_bounds__(256) void attn_scores(const float* __restrict__ qkv,
                                                   float* __restrict__ sc)
{
  int bh = blockIdx.z;
  int b = bh >> 3, h = bh & 7;
  int qt = blockIdx.y * 32, kt = blockIdx.x * 32;
  __shared__ float qs[32][33], ks[32][33];
  int r = threadIdx.x >> 3, dd = (threadIdx.x & 7) * 4;
  {
    int qi = qt + r;
    float4 v = make_float4(0.f, 0.f, 0.f, 0.f);
    if (qi < kQ) v = *reinterpret_cast<const float4*>(qkv + (size_t)(b * kQ + qi) * 768 + h * 32 + dd);
    qs[r][dd] = v.x; qs[r][dd + 1] = v.y; qs[r][dd + 2] = v.z; qs[r][dd + 3] = v.w;
    int kj = kt + r;
    float4 w = make_float4(0.f, 0.f, 0.f, 0.f);
    if (kj < kQ) w = *reinterpret_cast<const float4*>(qkv + (size_t)(b * kQ + kj) * 768 + 256 + h * 32 + dd);
    ks[r][dd] = w.x; ks[r][dd + 1] = w.y; ks[r][dd + 2] = w.z; ks[r][dd + 3] = w.w;
  }
  __syncthreads();
  int ty = (threadIdx.x >> 4) * 2, tx = (threadIdx.x & 15) * 2;
  float acc[2][2] = {};
#pragma unroll
  for (int k = 0; k < 32; ++k) {
    float a0 = qs[ty][k], a1 = qs[ty + 1][k];
    float b0 = ks[tx][k], b1 = ks[tx + 1][k];
    acc[0][0] += a0 * b0; acc[0][1] += a0 * b1;
    acc[1][0] += a1 * b0; acc[1][1] += a1 * b1;
  }
  const float scale = 0.17677669529663687f;  // 1/sqrt(32)
#pragma unroll
  for (int i = 0; i < 2; ++i) {
    int qi = qt + ty + i;
    if (qi >= kQ) continue;
#pragma unroll
    for (int j = 0; j < 2; ++j) {
      int kj = kt + tx + j;
      if (kj >= kQ) continue;
      sc[((size_t)bh * kQ + qi) * kQ + kj] = acc[i][j] * scale;
    }
  }
}

__global__ __launch_bounds__(256) void softmax_rows(float* __restrict__ sc)
{
  int wid = blockIdx.x * 4 + (threadIdx.x >> 6);
  int lane = threadIdx.x & 63;
  float* row = sc + (size_t)wid * kQ;
  float v[5];
  float m = -1e30f;
#pragma unroll
  for (int i = 0; i < 5; ++i) {
    int idx = lane + i * 64;
    v[i] = (idx < kQ) ? row[idx] : -1e30f;
    m = fmaxf(m, v[i]);
  }
#pragma unroll
  for (int o = 32; o; o >>= 1) m = fmaxf(m, __shfl_xor(m, o));
  float s = 0.f;
#pragma unroll
  for (int i = 0; i < 5; ++i) { v[i] = expf(v[i] - m); s += v[i]; }
#pragma unroll
  for (int o = 32; o; o >>= 1) s += __shfl_xor(s, o);
  float inv = 1.f / s;
#pragma unroll
  for (int i = 0; i < 5; ++i) {
    int idx = lane + i * 64;
    if (idx < kQ) row[idx] = v[i] * inv;
  }
}

__global__ __launch_bounds__(256) void attn_pv(const float* __restrict__ qkv,
                                               const float* __restrict__ att,
                                               float* __restrict__ outp)
{
  int bh = blockIdx.y;
  int b = bh >> 3, h = bh & 7;
  __shared__ float vs[300][32];
  int d = threadIdx.x & 31;
  for (int k = threadIdx.x >> 5; k < kQ; k += 8)
    vs[k][d] = qkv[(size_t)(b * kQ + k) * 768 + 512 + h * 32 + d];
  __syncthreads();
  int qr = threadIdx.x >> 5;
  int qend = (kQ < (int)(blockIdx.x * 64 + 64)) ? kQ : (int)(blockIdx.x * 64 + 64);
  for (int q = blockIdx.x * 64 + qr; q < qend; q += 8) {
    const float* arow = att + ((size_t)bh * kQ + q) * kQ;
    float acc = 0.f;
    for (int k = 0; k < kQ; ++k) acc += arow[k] * vs[k][d];
    outp[(size_t)(b * kQ + q) * 256 + h * 32 + d] = acc;
  }
}

__global__ void softmax16_kernel(float* __restrict__ x)
{
  int r = blockIdx.x * 256 + threadIdx.x;
  if (r >= kBQ * kH) return;
  float* p = x + (size_t)r * 16;
  float m = -1e30f;
#pragma unroll
  for (int k = 0; k < 16; ++k) m = fmaxf(m, p[k]);
  float s = 0.f;
  float e[16];
#pragma unroll
  for (int k = 0; k < 16; ++k) { e[k] = expf(p[k] - m); s += e[k]; }
  float inv = 1.f / s;
#pragma unroll
  for (int k = 0; k < 16; ++k) p[k] = e[k] * inv;
}

// ---------------- MSDA: val bf16 -> fp32 out ----------------
__global__ __launch_bounds__(256) void msda_kernel(
    const ushort* __restrict__ val, const float* __restrict__ off,
    const float* __restrict__ aw, const float* __restrict__ ref,
    const float* __restrict__ vr, float* __restrict__ outp)
{
  int bq = blockIdx.x;
  int b = bq / kQ;
  int h = threadIdx.x >> 5, d = threadIdx.x & 31;
  const int HL[4] = {80, 40, 20, 10};
  const int ST[4] = {0, 6400, 8000, 8400};
  float r0 = ref[bq * 4 + 0], r1 = ref[bq * 4 + 1];
  float r2 = ref[bq * 4 + 2], r3 = ref[bq * 4 + 3];
  const float* offrow = off + (size_t)bq * 256 + h * 32;
  const float* awrow = aw + (size_t)bq * 128 + h * 16;
  float acc = 0.f;
#pragma unroll
  for (int l = 0; l < 4; ++l) {
    int Wl = HL[l], Hl = HL[l];
    float vrx = vr[(b * 4 + l) * 2 + 0], vry = vr[(b * 4 + l) * 2 + 1];
    float cx = r0 * vrx, cy = r1 * vry;
    float sw = r2 * vrx * 0.125f, sh = r3 * vry * 0.125f;
    const ushort* vbase = val + ((size_t)b * kS + ST[l]) * 256 + h * 32 + d;
#pragma unroll
    for (int p = 0; p < 4; ++p) {
      float ox = offrow[l * 8 + p * 2 + 0];
      float oy = offrow[l * 8 + p * 2 + 1];
      float x = (cx + ox * sw) * Wl - 0.5f;
      float y = (cy + oy * sh) * Hl - 0.5f;
      float x0f = floorf(x), y0f = floorf(y);
      int x0 = (int)x0f, y0 = (int)y0f;
      float fx = x - x0f, fy = y - y0f;
      float a = awrow[l * 4 + p];
#pragma unroll
      for (int dy = 0; dy < 2; ++dy) {
#pragma unroll
        for (int dx = 0; dx < 2; ++dx) {
          int xi = x0 + dx, yi = y0 + dy;
          if (xi < 0 || xi >= Wl || yi < 0 || yi >= Hl) continue;
          float w = (dx ? fx : 1.f - fx) * (dy ? fy : 1.f - fy);
          acc += a * w * bf2f(vbase[(size_t)(yi * Wl + xi) * 256]);
        }
      }
    }
  }
  outp[(size_t)bq * 256 + h * 32 + d] = acc;
}

// ---------------- box head final ----------------
__global__ void box_final(const float* __restrict__ bh2, const float* __restrict__ W3,
                          const float* __restrict__ b3, const float* __restrict__ ref,
                          float* __restrict__ outb)
{
  int i = blockIdx.x * 256 + threadIdx.x;
  if (i >= kBQ * 4) return;
  int rc = i >> 2, c = i & 3;
  const float* rowp = bh2 + (size_t)rc * 256;
  float acc = b3[c];
  for (int k = 0; k < 256; ++k) acc += rowp[k] * W3[k * 4 + c];
  float r = ref[i];
  r = fminf(fmaxf(r, 0.f), 1.f);
  float inv = logf(fmaxf(r, 1e-5f)) - logf(fmaxf(1.f - r, 1e-5f));
  outb[i] = 1.f / (1.f + expf(-(acc + inv)));
}

extern "C" void kernel_launch(void* const* d_in, const int* in_sizes, int n_in,
                              void* d_out, int out_size, void* d_ws, size_t ws_size,
                              hipStream_t stream)
{
  const float* target  = (const float*)d_in[0];
  const float* rpu     = (const float*)d_in[1];
  const float* memory  = (const float*)d_in[2];
  const float* vr      = (const float*)d_in[3];
  const float* sa_Wqkv = (const float*)d_in[4];
  const float* sa_bqkv = (const float*)d_in[5];
  const float* sa_Wo   = (const float*)d_in[6];
  const float* sa_bo   = (const float*)d_in[7];
  const float* ca_Woff = (const float*)d_in[8];
  const float* ca_boff = (const float*)d_in[9];
  const float* ca_Wattn= (const float*)d_in[10];
  const float* ca_battn= (const float*)d_in[11];
  const float* ca_Wv   = (const float*)d_in[12];
  const float* ca_bv   = (const float*)d_in[13];
  const float* ca_Wout = (const float*)d_in[14];
  const float* ca_bout = (const float*)d_in[15];
  const float* ffn_W1  = (const float*)d_in[16];
  const float* ffn_b1  = (const float*)d_in[17];
  const float* ffn_W2  = (const float*)d_in[18];
  const float* ffn_b2  = (const float*)d_in[19];
  const float* ln1_g   = (const float*)d_in[20];
  const float* ln1_b   = (const float*)d_in[21];
  const float* ln2_g   = (const float*)d_in[22];
  const float* ln2_b   = (const float*)d_in[23];
  const float* ln3_g   = (const float*)d_in[24];
  const float* ln3_b   = (const float*)d_in[25];
  const float* norm_g  = (const float*)d_in[26];
  const float* norm_b  = (const float*)d_in[27];
  const float* qpos_W1 = (const float*)d_in[28];
  const float* qpos_b1 = (const float*)d_in[29];
  const float* qpos_W2 = (const float*)d_in[30];
  const float* qpos_b2 = (const float*)d_in[31];
  const float* cls_W   = (const float*)d_in[32];
  const float* cls_b   = (const float*)d_in[33];
  const float* box_W1  = (const float*)d_in[34];
  const float* box_b1  = (const float*)d_in[35];
  const float* box_W2  = (const float*)d_in[36];
  const float* box_b2  = (const float*)d_in[37];
  const float* box_W3  = (const float*)d_in[38];
  const float* box_b3  = (const float*)d_in[39];

  char* wsb = (char*)d_ws;
  // ---- arena [0, 34,816,000): pe/qkv/scores... aliased with val_bf ----
  float*  pe     = (float*) (wsb + 0);          // 2400*512 f32  = 4,915,200 B
  float*  qkv    = (float*) (wsb + 4915200);    // 2400*768 f32  = 7,372,800 B
  float*  qposh  = (float*) (wsb + 12288000);   // 2400*256 f32  = 2,457,600 B
  ushort* val_bf = (ushort*)(wsb + 0);          // 68000*256 bf16= 34,816,000 B
  // scores kept outside arena (val region too small to also hold it safely)
  // ---- persistent ----
  size_t P = 34816000;
  float*  output = (float*)(wsb + P);             // 2,457,600
  float*  qpos   = (float*)(wsb + P + 2457600);   // 2,457,600
  float*  head   = (float*)(wsb + P + 4915200);   // 2,457,600
  float*  tmp    = (float*)(wsb + P + 7372800);   // 2,457,600 (alias bh2)
  float*  offb   = (float*)(wsb + P + 9830400);   // 2,457,600 (alias nob)
  float*  awb    = (float*)(wsb + P + 12288000);  // 1,228,800
  float*  ffnh   = (float*)(wsb + P + 13516800);  // 9,830,400
  float*  bh1    = (float*)(wsb + P + 23347200);  // 2,457,600
  float*  ref0   = (float*)(wsb + P + 25804800);  // 38,400
  float*  scores = (float*)(wsb + P + 25843200);  // 64*300*300 f32 = 23,040,000
  float*  bh2 = tmp;
  float*  nob = offb;
  // ---- split weights: hi then lo (7,274,496 ushorts each) ----
  ushort* wHI = (ushort*)(wsb + P + 25843200 + 23040000);
  ushort* wLO = wHI + 7274496;

  ushort* wq_h    = wHI + 0,       *wq_l    = wLO + 0;        // (L,768,256)
  ushort* wo_h    = wHI + 1179648, *wo_l    = wLO + 1179648;  // (L,256,256)
  ushort* woff_h  = wHI + 1572864, *woff_l  = wLO + 1572864;  // (L,256,256)
  ushort* wattn_h = wHI + 1966080, *wattn_l = wLO + 1966080;  // (L,128,256)
  ushort* wv_h    = wHI + 2162688, *wv_l    = wLO + 2162688;  // (L,256,256)
  ushort* wout_h  = wHI + 2555904, *wout_l  = wLO + 2555904;  // (L,256,256)
  ushort* w1_h    = wHI + 2949120, *w1_l    = wLO + 2949120;  // (L,1024,256)
  ushort* w2_h    = wHI + 4521984, *w2_l    = wLO + 4521984;  // (L,256,1024)
  ushort* wq1_h   = wHI + 6094848, *wq1_l   = wLO + 6094848;  // (256,512)
  ushort* wq2_h   = wHI + 6225920, *wq2_l   = wLO + 6225920;  // (256,256)
  ushort* wb1_h   = wHI + 6291456, *wb1_l   = wLO + 6291456;  // (L,256,256)
  ushort* wb2_h   = wHI + 6684672, *wb2_l   = wLO + 6684672;  // (L,256,256)
  ushort* wcls_h  = wHI + 7077888, *wcls_l  = wLO + 7077888;  // (L,128pad,256)

  // ---- once per launch: transpose + hi/lo split (+pad for cls) ----
  transpose_split_pad<<<dim3(24, 8, 6), 256, 0, stream>>>(sa_Wqkv, wq_h, wq_l, 256, 768, 768);
  transpose_split_pad<<<dim3(8, 8, 6), 256, 0, stream>>>(sa_Wo, wo_h, wo_l, 256, 256, 256);
  transpose_split_pad<<<dim3(8, 8, 6), 256, 0, stream>>>(ca_Woff, woff_h, woff_l, 256, 256, 256);
  transpose_split_pad<<<dim3(4, 8, 6), 256, 0, stream>>>(ca_Wattn, wattn_h, wattn_l, 256, 128, 128);
  transpose_split_pad<<<dim3(8, 8, 6), 256, 0, stream>>>(ca_Wv, wv_h, wv_l, 256, 256, 256);
  transpose_split_pad<<<dim3(8, 8, 6), 256, 0, stream>>>(ca_Wout, wout_h, wout_l, 256, 256, 256);
  transpose_split_pad<<<dim3(32, 8, 6), 256, 0, stream>>>(ffn_W1, w1_h, w1_l, 256, 1024, 1024);
  transpose_split_pad<<<dim3(8, 32, 6), 256, 0, stream>>>(ffn_W2, w2_h, w2_l, 1024, 256, 256);
  transpose_split_pad<<<dim3(8, 16, 1), 256, 0, stream>>>(qpos_W1, wq1_h, wq1_l, 512, 256, 256);
  transpose_split_pad<<<dim3(8, 8, 1), 256, 0, stream>>>(qpos_W2, wq2_h, wq2_l, 256, 256, 256);
  transpose_split_pad<<<dim3(8, 8, 6), 256, 0, stream>>>(box_W1, wb1_h, wb1_l, 256, 256, 256);
  transpose_split_pad<<<dim3(8, 8, 6), 256, 0, stream>>>(box_W2, wb2_h, wb2_l, 256, 256, 256);
  transpose_split_pad<<<dim3(4, 8, 6), 256, 0, stream>>>(cls_W, wcls_h, wcls_l, 256, 80, 128);

  hipMemcpyAsync(output, target, sizeof(float) * kBQ * kC, hipMemcpyDeviceToDevice, stream);
  sigmoid_kernel<<<(kBQ * 4 + 255) / 256, 256, 0, stream>>>(rpu, ref0, kBQ * 4);

  float* boxes_out  = (float*)d_out;                  // (L,B,Q,4)
  float* logits_out = (float*)d_out + kL * kBQ * 4;   // (L,B,Q,80)

  const float* ref = ref0;
  for (int i = 0; i < kL; ++i) {
    // positional embedding + qpos MLP
    pe_kernel<<<(kBQ * 512 + 255) / 256, 256, 0, stream>>>(ref, vr, pe);
    gemm_x3<<<dim3(4, 38), 256, 0, stream>>>(pe, nullptr, wq1_h, wq1_l, qpos_b1,
                                             qposh, kBQ, 256, 256, 512, 1);
    gemm_x3<<<dim3(4, 38), 256, 0, stream>>>(qposh, nullptr, wq2_h, wq2_l, qpos_b2,
                                             qpos, kBQ, 256, 256, 256, 0);
    // self-attention (q = output + qpos fused in staging)
    gemm_x3<<<dim3(12, 38), 256, 0, stream>>>(output, qpos, wq_h + (size_t)i * 196608,
                                              wq_l + (size_t)i * 196608,
                                              sa_bqkv + i * 768, qkv, kBQ, 768, 768, 256, 0);
    attn_scores<<<dim3(10, 10, 64), 256, 0, stream>>>(qkv, scores);
    softmax_rows<<<4800, 256, 0, stream>>>(scores);
    attn_pv<<<dim3(5, 64), 256, 0, stream>>>(qkv, scores, head);
    gemm_x3<<<dim3(4, 38), 256, 0, stream>>>(head, nullptr, wo_h + (size_t)i * 65536,
                                             wo_l + (size_t)i * 65536,
                                             sa_bo + i * kC, tmp, kBQ, 256, 256, 256, 0);
    ln_kernel<<<kBQ, 256, 0, stream>>>(output, tmp, ln1_g + i * kC, ln1_b + i * kC, output);
    // cross-attention (MSDA); q = output + qpos fused in staging
    gemm_x3<<<dim3(4, 38), 256, 0, stream>>>(output, qpos, woff_h + (size_t)i * 65536,
                                             woff_l + (size_t)i * 65536,
                                             ca_boff + i * 256, offb, kBQ, 256, 256, 256, 0);
    gemm_x3<<<dim3(2, 38), 256, 0, stream>>>(output, qpos, wattn_h + (size_t)i * 32768,
                                             wattn_l + (size_t)i * 32768,
                                             ca_battn + i * 128, awb, kBQ, 128, 128, 256, 0);
    softmax16_kernel<<<(kBQ * kH + 255) / 256, 256, 0, stream>>>(awb);
    gemm_val<<<1063, 256, 0, stream>>>(memory, wv_h + (size_t)i * 65536,
                                       ca_bv + i * kC, val_bf, kB * kS);
    msda_kernel<<<kBQ, 256, 0, stream>>>(val_bf, offb, awb, ref, vr, head);
    gemm_x3<<<dim3(4, 38), 256, 0, stream>>>(head, nullptr, wout_h + (size_t)i * 65536,
                                             wout_l + (size_t)i * 65536,
                                             ca_bout + i * kC, tmp, kBQ, 256, 256, 256, 0);
    ln_kernel<<<kBQ, 256, 0, stream>>>(output, tmp, ln2_g + i * kC, ln2_b + i * kC, output);
    // FFN
    gemm_x3<<<dim3(16, 38), 256, 0, stream>>>(output, nullptr, w1_h + (size_t)i * 262144,
                                              w1_l + (size_t)i * 262144,
                                              ffn_b1 + i * kF, ffnh, kBQ, kF, kF, 256, 1);
    gemm_x3<<<dim3(4, 38), 256, 0, stream>>>(ffnh, nullptr, w2_h + (size_t)i * 262144,
                                             w2_l + (size_t)i * 262144,
                                             ffn_b2 + i * kC, tmp, kBQ, 256, 256, kF, 0);
    ln_kernel<<<kBQ, 256, 0, stream>>>(output, tmp, ln3_g + i * kC, ln3_b + i * kC, output);
    // heads
    ln_kernel<<<kBQ, 256, 0, stream>>>(output, nullptr, norm_g, norm_b, nob);
    gemm_x3<<<dim3(4, 38), 256, 0, stream>>>(nob, nullptr, wb1_h + (size_t)i * 65536,
                                             wb1_l + (size_t)i * 65536,
                                             box_b1 + i * kC, bh1, kBQ, 256, 256, 256, 1);
    gemm_x3<<<dim3(4, 38), 256, 0, stream>>>(bh1, nullptr, wb2_h + (size_t)i * 65536,
                                             wb2_l + (size_t)i * 65536,
                                             box_b2 + i * kC, bh2, kBQ, 256, 256, 256, 1);
    box_final<<<(kBQ * 4 + 255) / 256, 256, 0, stream>>>(bh2, box_W3 + (size_t)i * kC * 4,
                                                         box_b3 + i * 4, ref,
                                                         boxes_out + (size_t)i * kBQ * 4);
    gemm_x3<<<dim3(2, 38), 256, 0, stream>>>(nob, nullptr, wcls_h + (size_t)i * 32768,
                                             wcls_l + (size_t)i * 32768,
                                             cls_b + i * kNC,
                                             logits_out + (size_t)i * kBQ * kNC,
                                             kBQ, 128, kNC, 256, 0);
    ref = boxes_out + (size_t)i * kBQ * 4;
  }
}

// Round 8
// 1802.631 us; speedup vs baseline: 2.7081x; 1.2137x over previous
//
#include <hip/hip_runtime.h>

// RT-DETR decoder, round 8 = round 7 with the attn_fused PV overflow fixed.
// Bug: P/Vt row stride was 312 halfs but the PV k-loop covers k in [0,320)
// (10 MFMA steps x 32) -> ks=9,lg=3 read past the row into the next row's
// live data. Fix: stride 328 (>=320, mult-of-8 for b128 alignment, 164 words
// == 4 mod 32 so rows spread across banks), zero pad cols 304..327.
// All other kernels identical to round 7 (merged off+attn GEMM, dual box1+cls).

static constexpr int kB = 8, kQ = 300, kC = 256, kH = 8, kL = 6,
                     kF = 1024, kNC = 80, kS = 8500;
static constexpr int kBQ = kB * kQ;  // 2400

typedef __attribute__((ext_vector_type(8))) short short8v;
typedef __attribute__((ext_vector_type(8))) _Float16 half8v;
typedef __attribute__((ext_vector_type(4))) float floatx4;

__device__ inline ushort f2bf(float f) {
  unsigned u = __float_as_uint(f);
  u += 0x7fff + ((u >> 16) & 1);
  return (ushort)(u >> 16);
}
__device__ inline float bf2f(ushort h) { return __uint_as_float((unsigned)h << 16); }

// ------- weight transpose + hi/lo split + concat/pad: Wt[rowOff+n][k] --------
__global__ __launch_bounds__(256) void transpose_split_cat(
    const float* __restrict__ W, ushort* __restrict__ Whi,
    ushort* __restrict__ Wlo, int K, int N, int rowOff, int NtotRows)
{
  __shared__ float t[32][33];
  size_t matI = (size_t)blockIdx.z * K * N;
  size_t matO = (size_t)blockIdx.z * NtotRows * K;
  int n0 = blockIdx.x * 32, k0 = blockIdx.y * 32;
  int tx = threadIdx.x & 31, ty = threadIdx.x >> 5;  // ty 0..7
#pragma unroll
  for (int dy = 0; dy < 32; dy += 8) {
    int n = n0 + tx;
    t[ty + dy][tx] = (n < N) ? W[matI + (size_t)(k0 + ty + dy) * N + n] : 0.f;
  }
  __syncthreads();
#pragma unroll
  for (int dy = 0; dy < 32; dy += 8) {
    float v = t[tx][ty + dy];
    ushort h = f2bf(v);
    size_t o = matO + (size_t)(rowOff + n0 + ty + dy) * K + k0 + tx;
    Whi[o] = h;
    Wlo[o] = f2bf(v - bf2f(h));
  }
}

__global__ void concat_bias(const float* __restrict__ a, int na,
                            const float* __restrict__ b, int nb,
                            float* __restrict__ out, int ntot, int total)
{
  int i = blockIdx.x * 256 + threadIdx.x;
  if (i >= total) return;
  int z = i / ntot, c = i % ntot;
  float v = 0.f;
  if (c < na) v = a[z * na + c];
  else if (c - na < nb) v = b[z * nb + (c - na)];
  out[i] = v;
}

// ------- bf16x3 GEMM: out = act((A[+A2])@Bt^T + bias) ------------------------
__global__ __launch_bounds__(256) void gemm_x3(
    const float* __restrict__ A, const float* __restrict__ A2,
    const ushort* __restrict__ Bhi, const ushort* __restrict__ Blo,
    const float* __restrict__ bias, float* __restrict__ out,
    int M, int N, int Nout, int K, int relu)
{
  __shared__ ushort Ah[64 * 64], Al[64 * 64], Bh[64 * 64], Bl[64 * 64];
  int tid = threadIdx.x;
  int tm = blockIdx.y * 64, tn = blockIdx.x * 64;
  int lane = tid & 63, wid = tid >> 6;
  int wr = wid >> 1, wc = wid & 1;
  int lrow = lane & 15, lk = lane >> 4;
  floatx4 acc[2][2] = {};
  for (int k0 = 0; k0 < K; k0 += 64) {
#pragma unroll
    for (int it = 0; it < 2; ++it) {
      int s = tid + it * 256;
      int row = s >> 3, cphys = s & 7;
      int clog = cphys ^ (row & 7);
      int gr = tm + row; if (gr > M - 1) gr = M - 1;
      const float* gp = A + (size_t)gr * K + k0 + clog * 8;
      float4 v0 = *(const float4*)gp;
      float4 v1 = *(const float4*)(gp + 4);
      float a[8] = {v0.x, v0.y, v0.z, v0.w, v1.x, v1.y, v1.z, v1.w};
      if (A2) {
        const float* gp2 = A2 + (size_t)gr * K + k0 + clog * 8;
        float4 w0 = *(const float4*)gp2;
        float4 w1 = *(const float4*)(gp2 + 4);
        a[0] += w0.x; a[1] += w0.y; a[2] += w0.z; a[3] += w0.w;
        a[4] += w1.x; a[5] += w1.y; a[6] += w1.z; a[7] += w1.w;
      }
      ushort h[8], l[8];
#pragma unroll
      for (int j = 0; j < 8; ++j) {
        h[j] = f2bf(a[j]);
        l[j] = f2bf(a[j] - bf2f(h[j]));
      }
      *(uint4*)&Ah[s * 8] = *(const uint4*)h;
      *(uint4*)&Al[s * 8] = *(const uint4*)l;
      size_t bo = (size_t)(tn + row) * K + k0 + clog * 8;
      *(uint4*)&Bh[s * 8] = *(const uint4*)(Bhi + bo);
      *(uint4*)&Bl[s * 8] = *(const uint4*)(Blo + bo);
    }
    __syncthreads();
#pragma unroll
    for (int ks = 0; ks < 2; ++ks) {
      short8v fah[2], fal[2], fbh[2], fbl[2];
#pragma unroll
      for (int mi = 0; mi < 2; ++mi) {
        int row = wr * 32 + mi * 16 + lrow;
        int c = ks * 4 + lk;
        int p = row * 8 + (c ^ (row & 7));
        fah[mi] = *(const short8v*)&Ah[p * 8];
        fal[mi] = *(const short8v*)&Al[p * 8];
      }
#pragma unroll
      for (int ni = 0; ni < 2; ++ni) {
        int row = wc * 32 + ni * 16 + lrow;
        int c = ks * 4 + lk;
        int p = row * 8 + (c ^ (row & 7));
        fbh[ni] = *(const short8v*)&Bh[p * 8];
        fbl[ni] = *(const short8v*)&Bl[p * 8];
      }
#pragma unroll
      for (int mi = 0; mi < 2; ++mi)
#pragma unroll
        for (int ni = 0; ni < 2; ++ni) {
          acc[mi][ni] = __builtin_amdgcn_mfma_f32_16x16x32_bf16(
              fah[mi], fbh[ni], acc[mi][ni], 0, 0, 0);
          acc[mi][ni] = __builtin_amdgcn_mfma_f32_16x16x32_bf16(
              fal[mi], fbh[ni], acc[mi][ni], 0, 0, 0);
          acc[mi][ni] = __builtin_amdgcn_mfma_f32_16x16x32_bf16(
              fah[mi], fbl[ni], acc[mi][ni], 0, 0, 0);
        }
    }
    __syncthreads();
  }
#pragma unroll
  for (int mi = 0; mi < 2; ++mi) {
#pragma unroll
    for (int j = 0; j < 4; ++j) {
      int grow = tm + wr * 32 + mi * 16 + lk * 4 + j;
      if (grow >= M) continue;
#pragma unroll
      for (int ni = 0; ni < 2; ++ni) {
        int gcol = tn + wc * 32 + ni * 16 + lrow;
        if (gcol >= Nout) continue;
        float v = acc[mi][ni][j] + bias[gcol];
        if (relu) v = fmaxf(v, 0.f);
        out[(size_t)grow * Nout + gcol] = v;
      }
    }
  }
}

// ------- dual-output bf16x3 GEMM (box1+cls): cols<N1 -> out1(relu), rest out2
__global__ __launch_bounds__(256) void gemm_x3_dual(
    const float* __restrict__ A, const ushort* __restrict__ Bhi,
    const ushort* __restrict__ Blo, const float* __restrict__ bias,
    float* __restrict__ out1, int N1, float* __restrict__ out2, int N2,
    int M, int K)
{
  __shared__ ushort Ah[64 * 64], Al[64 * 64], Bh[64 * 64], Bl[64 * 64];
  int tid = threadIdx.x;
  int tm = blockIdx.y * 64, tn = blockIdx.x * 64;
  int lane = tid & 63, wid = tid >> 6;
  int wr = wid >> 1, wc = wid & 1;
  int lrow = lane & 15, lk = lane >> 4;
  floatx4 acc[2][2] = {};
  for (int k0 = 0; k0 < K; k0 += 64) {
#pragma unroll
    for (int it = 0; it < 2; ++it) {
      int s = tid + it * 256;
      int row = s >> 3, cphys = s & 7;
      int clog = cphys ^ (row & 7);
      int gr = tm + row; if (gr > M - 1) gr = M - 1;
      const float* gp = A + (size_t)gr * K + k0 + clog * 8;
      float4 v0 = *(const float4*)gp;
      float4 v1 = *(const float4*)(gp + 4);
      float a[8] = {v0.x, v0.y, v0.z, v0.w, v1.x, v1.y, v1.z, v1.w};
      ushort h[8], l[8];
#pragma unroll
      for (int j = 0; j < 8; ++j) {
        h[j] = f2bf(a[j]);
        l[j] = f2bf(a[j] - bf2f(h[j]));
      }
      *(uint4*)&Ah[s * 8] = *(const uint4*)h;
      *(uint4*)&Al[s * 8] = *(const uint4*)l;
      size_t bo = (size_t)(tn + row) * K + k0 + clog * 8;
      *(uint4*)&Bh[s * 8] = *(const uint4*)(Bhi + bo);
      *(uint4*)&Bl[s * 8] = *(const uint4*)(Blo + bo);
    }
    __syncthreads();
#pragma unroll
    for (int ks = 0; ks < 2; ++ks) {
      short8v fah[2], fal[2], fbh[2], fbl[2];
#pragma unroll
      for (int mi = 0; mi < 2; ++mi) {
        int row = wr * 32 + mi * 16 + lrow;
        int c = ks * 4 + lk;
        int p = row * 8 + (c ^ (row & 7));
        fah[mi] = *(const short8v*)&Ah[p * 8];
        fal[mi] = *(const short8v*)&Al[p * 8];
      }
#pragma unroll
      for (int ni = 0; ni < 2; ++ni) {
        int row = wc * 32 + ni * 16 + lrow;
        int c = ks * 4 + lk;
        int p = row * 8 + (c ^ (row & 7));
        fbh[ni] = *(const short8v*)&Bh[p * 8];
        fbl[ni] = *(const short8v*)&Bl[p * 8];
      }
#pragma unroll
      for (int mi = 0; mi < 2; ++mi)
#pragma unroll
        for (int ni = 0; ni < 2; ++ni) {
          acc[mi][ni] = __builtin_amdgcn_mfma_f32_16x16x32_bf16(
              fah[mi], fbh[ni], acc[mi][ni], 0, 0, 0);
          acc[mi][ni] = __builtin_amdgcn_mfma_f32_16x16x32_bf16(
              fal[mi], fbh[ni], acc[mi][ni], 0, 0, 0);
          acc[mi][ni] = __builtin_amdgcn_mfma_f32_16x16x32_bf16(
              fah[mi], fbl[ni], acc[mi][ni], 0, 0, 0);
        }
    }
    __syncthreads();
  }
#pragma unroll
  for (int mi = 0; mi < 2; ++mi) {
#pragma unroll
    for (int j = 0; j < 4; ++j) {
      int grow = tm + wr * 32 + mi * 16 + lk * 4 + j;
      if (grow >= M) continue;
#pragma unroll
      for (int ni = 0; ni < 2; ++ni) {
        int gcol = tn + wc * 32 + ni * 16 + lrow;
        float v = acc[mi][ni][j] + bias[gcol];
        if (gcol < N1) {
          out1[(size_t)grow * N1 + gcol] = fmaxf(v, 0.f);
        } else {
          int c2 = gcol - N1;
          if (c2 < N2) out2[(size_t)grow * N2 + c2] = v;
        }
      }
    }
  }
}

// ------- val GEMM: full-N tile 64x256, plain bf16, A read once ---------------
__global__ __launch_bounds__(256) void gemm_val(
    const float* __restrict__ A, const ushort* __restrict__ Bt,
    const float* __restrict__ bias, ushort* __restrict__ outh, int M)
{
  __shared__ ushort At[64 * 64];
  __shared__ ushort Bs[256 * 64];
  int tid = threadIdx.x;
  int tm = blockIdx.x * 64;
  int lane = tid & 63, wid = tid >> 6;
  int lrow = lane & 15, lk = lane >> 4;
  floatx4 acc[16] = {};
  for (int k0 = 0; k0 < 256; k0 += 64) {
#pragma unroll
    for (int it = 0; it < 2; ++it) {
      int s = tid + it * 256;
      int row = s >> 3, cphys = s & 7, clog = cphys ^ (row & 7);
      int gr = tm + row; if (gr > M - 1) gr = M - 1;
      const float* gp = A + (size_t)gr * 256 + k0 + clog * 8;
      float4 v0 = *(const float4*)gp;
      float4 v1 = *(const float4*)(gp + 4);
      ushort* dst = &At[s * 8];
      dst[0] = f2bf(v0.x); dst[1] = f2bf(v0.y); dst[2] = f2bf(v0.z); dst[3] = f2bf(v0.w);
      dst[4] = f2bf(v1.x); dst[5] = f2bf(v1.y); dst[6] = f2bf(v1.z); dst[7] = f2bf(v1.w);
    }
#pragma unroll
    for (int it = 0; it < 8; ++it) {
      int s = tid + it * 256;
      int row = s >> 3, cphys = s & 7, clog = cphys ^ (row & 7);
      *(uint4*)&Bs[s * 8] = *(const uint4*)(Bt + (size_t)row * 256 + k0 + clog * 8);
    }
    __syncthreads();
#pragma unroll
    for (int ks = 0; ks < 2; ++ks) {
      int c = ks * 4 + lk;
      int arow = wid * 16 + lrow;
      short8v af = *(const short8v*)&At[(arow * 8 + (c ^ (arow & 7))) * 8];
#pragma unroll
      for (int nf = 0; nf < 16; ++nf) {
        int brow = nf * 16 + lrow;
        short8v bf = *(const short8v*)&Bs[(brow * 8 + (c ^ (brow & 7))) * 8];
        acc[nf] = __builtin_amdgcn_mfma_f32_16x16x32_bf16(af, bf, acc[nf], 0, 0, 0);
      }
    }
    __syncthreads();
  }
#pragma unroll
  for (int j = 0; j < 4; ++j) {
    int grow = tm + wid * 16 + lk * 4 + j;
    if (grow >= M) continue;
#pragma unroll
    for (int nf = 0; nf < 16; ++nf) {
      int gcol = nf * 16 + lrow;
      outh[(size_t)grow * 256 + gcol] = f2bf(acc[nf][j] + bias[gcol]);
    }
  }
}

// ------- fused MHA: per (qtile 64, b*h) block, fp16 MFMA, softmax in-reg -----
// Stride PST=328 halfs: >=320 (10 k-steps x 32 stay in-row), mult of 8 (16B
// aligned b128), 164 words == 4 mod 32 (rows spread across banks).
// LDS halfs: K[304][40] @0, Q[64][40] @12160 (phase1);
//            P[64][328] @0 (phase2, aliases K+Q); Vt[32][328] @20992.
__global__ __launch_bounds__(256) void attn_fused(const float* __restrict__ qkv,
                                                  float* __restrict__ outp)
{
  constexpr int PST = 328;
  __shared__ _Float16 smem[31488];  // 62,976 B
  _Float16* Ksm  = smem;
  _Float16* Qsm  = smem + 12160;
  _Float16* Psm  = smem;
  _Float16* Vtsm = smem + 20992;
  int tid = threadIdx.x;
  int bh = blockIdx.y, b = bh >> 3, h = bh & 7;
  int qbase = blockIdx.x * 64;
  int sub = tid >> 5, d = tid & 31;
  const float qscale = 0.17677669529663687f;  // 1/sqrt(32), folded into Q
  for (int r0 = 0; r0 < 64; r0 += 8) {
    int r = r0 + sub;
    int qg = qbase + r; if (qg > 299) qg = 299;
    Qsm[r * 40 + d] = (_Float16)(qkv[(size_t)(b * 300 + qg) * 768 + h * 32 + d] * qscale);
  }
  for (int r0 = 0; r0 < 304; r0 += 8) {
    int r = r0 + sub;
    int kg = (r > 299) ? 299 : r;
    const float* base = qkv + (size_t)(b * 300 + kg) * 768 + h * 32 + d;
    Ksm[r * 40 + d] = (_Float16)base[256];
    Vtsm[d * PST + r] = (_Float16)((r < 300) ? base[512] : 0.f);
  }
  for (int i = tid; i < 32 * 24; i += 256) {  // zero Vt k-pad cols 304..327
    int dd = i / 24, c = 304 + i % 24;
    Vtsm[dd * PST + c] = (_Float16)0.f;
  }
  __syncthreads();

  int w = tid >> 6, l = tid & 63, lr = l & 15, lg = l >> 4;
  floatx4 zero4 = {0.f, 0.f, 0.f, 0.f};
  // S = (Q*scale)K^T; 19 col-tiles, K-dim=32 = single MFMA each
  half8v qa = *(const half8v*)&Qsm[(w * 16 + lr) * 40 + lg * 8];
  floatx4 sacc[19];
#pragma unroll
  for (int nt = 0; nt < 19; ++nt) {
    half8v kb = *(const half8v*)&Ksm[(nt * 16 + lr) * 40 + lg * 8];
    sacc[nt] = __builtin_amdgcn_mfma_f32_16x16x32_f16(qa, kb, zero4, 0, 0, 0);
  }
  if (lr >= 12) {  // cols 300..303 of tile 18
    sacc[18][0] = -1e30f; sacc[18][1] = -1e30f;
    sacc[18][2] = -1e30f; sacc[18][3] = -1e30f;
  }
  // softmax: row q = w*16+lg*4+j lives in the 16 lanes sharing lg
  float mx[4] = {-1e30f, -1e30f, -1e30f, -1e30f};
#pragma unroll
  for (int nt = 0; nt < 19; ++nt)
#pragma unroll
    for (int j = 0; j < 4; ++j) mx[j] = fmaxf(mx[j], sacc[nt][j]);
#pragma unroll
  for (int off = 1; off < 16; off <<= 1)
#pragma unroll
    for (int j = 0; j < 4; ++j) mx[j] = fmaxf(mx[j], __shfl_xor(mx[j], off));
  float sm[4] = {0.f, 0.f, 0.f, 0.f};
#pragma unroll
  for (int nt = 0; nt < 19; ++nt)
#pragma unroll
    for (int j = 0; j < 4; ++j) {
      float p = __expf(sacc[nt][j] - mx[j]);
      sacc[nt][j] = p; sm[j] += p;
    }
#pragma unroll
  for (int off = 1; off < 16; off <<= 1)
#pragma unroll
    for (int j = 0; j < 4; ++j) sm[j] += __shfl_xor(sm[j], off);
  float inv[4];
#pragma unroll
  for (int j = 0; j < 4; ++j) inv[j] = 1.f / sm[j];
  __syncthreads();  // all K/Q reads done before P overwrites that region
#pragma unroll
  for (int nt = 0; nt < 19; ++nt)
#pragma unroll
    for (int j = 0; j < 4; ++j)
      Psm[(w * 16 + lg * 4 + j) * PST + nt * 16 + lr] =
          (_Float16)(sacc[nt][j] * inv[j]);
  for (int i = tid; i < 64 * 24; i += 256) {  // zero P k-pad cols 304..327
    int rr = i / 24, c = 304 + i % 24;
    Psm[rr * PST + c] = (_Float16)0.f;
  }
  __syncthreads();
  // O = P V : A=P rows q, B=Vt rows d; 10 k-steps cover k 0..319 (pad zeroed)
  floatx4 oacc[2] = {zero4, zero4};
#pragma unroll
  for (int ks = 0; ks < 10; ++ks) {
    half8v pa = *(const half8v*)&Psm[(w * 16 + lr) * PST + ks * 32 + lg * 8];
#pragma unroll
    for (int dt = 0; dt < 2; ++dt) {
      half8v vb = *(const half8v*)&Vtsm[(dt * 16 + lr) * PST + ks * 32 + lg * 8];
      oacc[dt] = __builtin_amdgcn_mfma_f32_16x16x32_f16(pa, vb, oacc[dt], 0, 0, 0);
    }
  }
#pragma unroll
  for (int dt = 0; dt < 2; ++dt)
#pragma unroll
    for (int j = 0; j < 4; ++j) {
      int qg = qbase + w * 16 + lg * 4 + j;
      if (qg < 300)
        outp[(size_t)(b * 300 + qg) * 256 + h * 32 + dt * 16 + lr] = oacc[dt][j];
    }
}

// ---------------- LayerNorm: out = LN(x + delta) * g + b ----------------
__global__ __launch_bounds__(256) void ln_kernel(
    const float* __restrict__ x, const float* __restrict__ delta,
    const float* __restrict__ g, const float* __restrict__ b,
    float* __restrict__ out)
{
  __shared__ float red[4];
  int row = blockIdx.x, t = threadIdx.x;
  size_t idx = (size_t)row * 256 + t;
  float v = x[idx] + (delta ? delta[idx] : 0.f);
  float s = v;
#pragma unroll
  for (int o = 32; o; o >>= 1) s += __shfl_xor(s, o);
  if ((t & 63) == 0) red[t >> 6] = s;
  __syncthreads();
  float mean = (red[0] + red[1] + red[2] + red[3]) * (1.f / 256.f);
  __syncthreads();
  float dv = v - mean;
  float s2 = dv * dv;
#pragma unroll
  for (int o = 32; o; o >>= 1) s2 += __shfl_xor(s2, o);
  if ((t & 63) == 0) red[t >> 6] = s2;
  __syncthreads();
  float var = (red[0] + red[1] + red[2] + red[3]) * (1.f / 256.f);
  out[idx] = dv * rsqrtf(var + 1e-5f) * g[t] + b[t];
}

__global__ void sigmoid_kernel(const float* __restrict__ x, float* __restrict__ o, int n)
{
  int i = blockIdx.x * 256 + threadIdx.x;
  if (i < n) o[i] = 1.f / (1.f + expf(-x[i]));
}

// ---------------- sine positional embedding (B,Q,512) fp32 ----------------
__global__ void pe_kernel(const float* __restrict__ ref, const float* __restrict__ vr,
                          float* __restrict__ pe)
{
  int idx = blockIdx.x * 256 + threadIdx.x;
  if (idx >= kBQ * 512) return;
  int ch = idx & 511, bq = idx >> 9;
  int b = bq / kQ;
  int c = ch >> 7, j = ch & 127, p = j >> 1;
  float pos = ref[bq * 4 + c] * vr[(b * 4 + 0) * 2 + (c & 1)];
  float dim = expf((float)p * (9.210340371976184f / 64.f));  // 10000^(p/64)
  float arg = pos * 6.283185307179586f / dim;
  pe[idx] = (j & 1) ? cosf(arg) : sinf(arg);
}

// softmax over 16 attn weights; offaw layout [bq][384], aw at +256+h*16
__global__ void softmax16_kernel(float* __restrict__ x)
{
  int r = blockIdx.x * 256 + threadIdx.x;
  if (r >= kBQ * kH) return;
  int bq = r >> 3, h = r & 7;
  float* p = x + (size_t)bq * 384 + 256 + h * 16;
  float m = -1e30f;
#pragma unroll
  for (int k = 0; k < 16; ++k) m = fmaxf(m, p[k]);
  float s = 0.f;
  float e[16];
#pragma unroll
  for (int k = 0; k < 16; ++k) { e[k] = expf(p[k] - m); s += e[k]; }
  float inv = 1.f / s;
#pragma unroll
  for (int k = 0; k < 16; ++k) p[k] = e[k] * inv;
}

// ---------------- MSDA: val bf16, offaw combined buffer -> fp32 out ----------
__global__ __launch_bounds__(256) void msda_kernel(
    const ushort* __restrict__ val, const float* __restrict__ offaw,
    const float* __restrict__ ref, const float* __restrict__ vr,
    float* __restrict__ outp)
{
  int bq = blockIdx.x;
  int b = bq / kQ;
  int h = threadIdx.x >> 5, d = threadIdx.x & 31;
  const int HL[4] = {80, 40, 20, 10};
  const int ST[4] = {0, 6400, 8000, 8400};
  float r0 = ref[bq * 4 + 0], r1 = ref[bq * 4 + 1];
  float r2 = ref[bq * 4 + 2], r3 = ref[bq * 4 + 3];
  const float* offrow = offaw + (size_t)bq * 384 + h * 32;
  const float* awrow  = offaw + (size_t)bq * 384 + 256 + h * 16;
  float acc = 0.f;
#pragma unroll
  for (int l = 0; l < 4; ++l) {
    int Wl = HL[l], Hl = HL[l];
    float vrx = vr[(b * 4 + l) * 2 + 0], vry = vr[(b * 4 + l) * 2 + 1];
    float cx = r0 * vrx, cy = r1 * vry;
    float sw = r2 * vrx * 0.125f, sh = r3 * vry * 0.125f;
    const ushort* vbase = val + ((size_t)b * kS + ST[l]) * 256 + h * 32 + d;
#pragma unroll
    for (int p = 0; p < 4; ++p) {
      float ox = offrow[l * 8 + p * 2 + 0];
      float oy = offrow[l * 8 + p * 2 + 1];
      float x = (cx + ox * sw) * Wl - 0.5f;
      float y = (cy + oy * sh) * Hl - 0.5f;
      float x0f = floorf(x), y0f = floorf(y);
      int x0 = (int)x0f, y0 = (int)y0f;
      float fx = x - x0f, fy = y - y0f;
      float a = awrow[l * 4 + p];
#pragma unroll
      for (int dy = 0; dy < 2; ++dy) {
#pragma unroll
        for (int dx = 0; dx < 2; ++dx) {
          int xi = x0 + dx, yi = y0 + dy;
          if (xi < 0 || xi >= Wl || yi < 0 || yi >= Hl) continue;
          float w = (dx ? fx : 1.f - fx) * (dy ? fy : 1.f - fy);
          acc += a * w * bf2f(vbase[(size_t)(yi * Wl + xi) * 256]);
        }
      }
    }
  }
  outp[(size_t)bq * 256 + h * 32 + d] = acc;
}

// ---------------- box head final ----------------
__global__ void box_final(const float* __restrict__ bh2, const float* __restrict__ W3,
                          const float* __restrict__ b3, const float* __restrict__ ref,
                          float* __restrict__ outb)
{
  int i = blockIdx.x * 256 + threadIdx.x;
  if (i >= kBQ * 4) return;
  int rc = i >> 2, c = i & 3;
  const float* rowp = bh2 + (size_t)rc * 256;
  float acc = b3[c];
  for (int k = 0; k < 256; ++k) acc += rowp[k] * W3[k * 4 + c];
  float r = ref[i];
  r = fminf(fmaxf(r, 0.f), 1.f);
  float inv = logf(fmaxf(r, 1e-5f)) - logf(fmaxf(1.f - r, 1e-5f));
  outb[i] = 1.f / (1.f + expf(-(acc + inv)));
}

extern "C" void kernel_launch(void* const* d_in, const int* in_sizes, int n_in,
                              void* d_out, int out_size, void* d_ws, size_t ws_size,
                              hipStream_t stream)
{
  const float* target  = (const float*)d_in[0];
  const float* rpu     = (const float*)d_in[1];
  const float* memory  = (const float*)d_in[2];
  const float* vr      = (const float*)d_in[3];
  const float* sa_Wqkv = (const float*)d_in[4];
  const float* sa_bqkv = (const float*)d_in[5];
  const float* sa_Wo   = (const float*)d_in[6];
  const float* sa_bo   = (const float*)d_in[7];
  const float* ca_Woff = (const float*)d_in[8];
  const float* ca_boff = (const float*)d_in[9];
  const float* ca_Wattn= (const float*)d_in[10];
  const float* ca_battn= (const float*)d_in[11];
  const float* ca_Wv   = (const float*)d_in[12];
  const float* ca_bv   = (const float*)d_in[13];
  const float* ca_Wout = (const float*)d_in[14];
  const float* ca_bout = (const float*)d_in[15];
  const float* ffn_W1  = (const float*)d_in[16];
  const float* ffn_b1  = (const float*)d_in[17];
  const float* ffn_W2  = (const float*)d_in[18];
  const float* ffn_b2  = (const float*)d_in[19];
  const float* ln1_g   = (const float*)d_in[20];
  const float* ln1_b   = (const float*)d_in[21];
  const float* ln2_g   = (const float*)d_in[22];
  const float* ln2_b   = (const float*)d_in[23];
  const float* ln3_g   = (const float*)d_in[24];
  const float* ln3_b   = (const float*)d_in[25];
  const float* norm_g  = (const float*)d_in[26];
  const float* norm_b  = (const float*)d_in[27];
  const float* qpos_W1 = (const float*)d_in[28];
  const float* qpos_b1 = (const float*)d_in[29];
  const float* qpos_W2 = (const float*)d_in[30];
  const float* qpos_b2 = (const float*)d_in[31];
  const float* cls_W   = (const float*)d_in[32];
  const float* cls_b   = (const float*)d_in[33];
  const float* box_W1  = (const float*)d_in[34];
  const float* box_b1  = (const float*)d_in[35];
  const float* box_W2  = (const float*)d_in[36];
  const float* box_b2  = (const float*)d_in[37];
  const float* box_W3  = (const float*)d_in[38];
  const float* box_b3  = (const float*)d_in[39];

  char* wsb = (char*)d_ws;
  // ---- arena [0, 34,816,000): pe/qkv/qposh aliased with val_bf ----
  float*  pe     = (float*) (wsb + 0);          // 4,915,200 B
  float*  qkv    = (float*) (wsb + 4915200);    // 7,372,800 B
  float*  qposh  = (float*) (wsb + 12288000);   // 2,457,600 B
  ushort* val_bf = (ushort*)(wsb + 0);          // 34,816,000 B
  // ---- persistent ----
  size_t P = 34816000;
  float*  output = (float*)(wsb + P);             // 2,457,600
  float*  qpos   = (float*)(wsb + P + 2457600);   // 2,457,600
  float*  head   = (float*)(wsb + P + 4915200);   // 2,457,600
  float*  tmp    = (float*)(wsb + P + 7372800);   // 2,457,600 (alias bh2)
  float*  offaw  = (float*)(wsb + P + 9830400);   // 3,686,400 (alias nob)
  float*  ffnh   = (float*)(wsb + P + 13516800);  // 9,830,400
  float*  bh1    = (float*)(wsb + P + 23347200);  // 2,457,600
  float*  ref0   = (float*)(wsb + P + 25804800);  // 38,400
  float*  boffattn = (float*)(wsb + P + 25843200);  // 9,216
  float*  bboxcls  = (float*)(wsb + P + 25852416);  // 9,216
  float*  bh2 = tmp;
  float*  nob = offaw;
  // ---- split weights: hi then lo (7,274,496 ushorts each) ----
  ushort* wHI = (ushort*)(wsb + P + 25861632);
  ushort* wLO = wHI + 7274496;

  ushort* wq_h    = wHI + 0,       *wq_l    = wLO + 0;        // (L,768,256)
  ushort* wo_h    = wHI + 1179648, *wo_l    = wLO + 1179648;  // (L,256,256)
  ushort* woa_h   = wHI + 1572864, *woa_l   = wLO + 1572864;  // (L,384,256) off+attn
  ushort* wv_h    = wHI + 2162688, *wv_l    = wLO + 2162688;  // (L,256,256)
  ushort* wout_h  = wHI + 2555904, *wout_l  = wLO + 2555904;  // (L,256,256)
  ushort* w1_h    = wHI + 2949120, *w1_l    = wLO + 2949120;  // (L,1024,256)
  ushort* w2_h    = wHI + 4521984, *w2_l    = wLO + 4521984;  // (L,256,1024)
  ushort* wq1_h   = wHI + 6094848, *wq1_l   = wLO + 6094848;  // (256,512)
  ushort* wq2_h   = wHI + 6225920, *wq2_l   = wLO + 6225920;  // (256,256)
  ushort* wbc_h   = wHI + 6291456, *wbc_l   = wLO + 6291456;  // (L,384,256) box1+cls
  ushort* wb2_h   = wHI + 6881280, *wb2_l   = wLO + 6881280;  // (L,256,256)

  // ---- once per launch: transpose + hi/lo split (+concat/pad) ----
  transpose_split_cat<<<dim3(24, 8, 6), 256, 0, stream>>>(sa_Wqkv, wq_h, wq_l, 256, 768, 0, 768);
  transpose_split_cat<<<dim3(8, 8, 6), 256, 0, stream>>>(sa_Wo, wo_h, wo_l, 256, 256, 0, 256);
  transpose_split_cat<<<dim3(8, 8, 6), 256, 0, stream>>>(ca_Woff, woa_h, woa_l, 256, 256, 0, 384);
  transpose_split_cat<<<dim3(4, 8, 6), 256, 0, stream>>>(ca_Wattn, woa_h, woa_l, 256, 128, 256, 384);
  transpose_split_cat<<<dim3(8, 8, 6), 256, 0, stream>>>(ca_Wv, wv_h, wv_l, 256, 256, 0, 256);
  transpose_split_cat<<<dim3(8, 8, 6), 256, 0, stream>>>(ca_Wout, wout_h, wout_l, 256, 256, 0, 256);
  transpose_split_cat<<<dim3(32, 8, 6), 256, 0, stream>>>(ffn_W1, w1_h, w1_l, 256, 1024, 0, 1024);
  transpose_split_cat<<<dim3(8, 32, 6), 256, 0, stream>>>(ffn_W2, w2_h, w2_l, 1024, 256, 0, 256);
  transpose_split_cat<<<dim3(8, 16, 1), 256, 0, stream>>>(qpos_W1, wq1_h, wq1_l, 512, 256, 0, 256);
  transpose_split_cat<<<dim3(8, 8, 1), 256, 0, stream>>>(qpos_W2, wq2_h, wq2_l, 256, 256, 0, 256);
  transpose_split_cat<<<dim3(8, 8, 6), 256, 0, stream>>>(box_W1, wbc_h, wbc_l, 256, 256, 0, 384);
  transpose_split_cat<<<dim3(4, 8, 6), 256, 0, stream>>>(cls_W, wbc_h, wbc_l, 256, 80, 256, 384);
  transpose_split_cat<<<dim3(8, 8, 6), 256, 0, stream>>>(box_W2, wb2_h, wb2_l, 256, 256, 0, 256);
  concat_bias<<<9, 256, 0, stream>>>(ca_boff, 256, ca_battn, 128, boffattn, 384, kL * 384);
  concat_bias<<<9, 256, 0, stream>>>(box_b1, 256, cls_b, 80, bboxcls, 384, kL * 384);

  hipMemcpyAsync(output, target, sizeof(float) * kBQ * kC, hipMemcpyDeviceToDevice, stream);
  sigmoid_kernel<<<(kBQ * 4 + 255) / 256, 256, 0, stream>>>(rpu, ref0, kBQ * 4);

  float* boxes_out  = (float*)d_out;                  // (L,B,Q,4)
  float* logits_out = (float*)d_out + kL * kBQ * 4;   // (L,B,Q,80)

  const float* ref = ref0;
  for (int i = 0; i < kL; ++i) {
    // positional embedding + qpos MLP
    pe_kernel<<<(kBQ * 512 + 255) / 256, 256, 0, stream>>>(ref, vr, pe);
    gemm_x3<<<dim3(4, 38), 256, 0, stream>>>(pe, nullptr, wq1_h, wq1_l, qpos_b1,
                                             qposh, kBQ, 256, 256, 512, 1);
    gemm_x3<<<dim3(4, 38), 256, 0, stream>>>(qposh, nullptr, wq2_h, wq2_l, qpos_b2,
                                             qpos, kBQ, 256, 256, 256, 0);
    // self-attention (q = output + qpos fused in staging; fused MHA kernel)
    gemm_x3<<<dim3(12, 38), 256, 0, stream>>>(output, qpos, wq_h + (size_t)i * 196608,
                                              wq_l + (size_t)i * 196608,
                                              sa_bqkv + i * 768, qkv, kBQ, 768, 768, 256, 0);
    attn_fused<<<dim3(5, 64), 256, 0, stream>>>(qkv, head);
    gemm_x3<<<dim3(4, 38), 256, 0, stream>>>(head, nullptr, wo_h + (size_t)i * 65536,
                                             wo_l + (size_t)i * 65536,
                                             sa_bo + i * kC, tmp, kBQ, 256, 256, 256, 0);
    ln_kernel<<<kBQ, 256, 0, stream>>>(output, tmp, ln1_g + i * kC, ln1_b + i * kC, output);
    // cross-attention (MSDA): merged off+attn GEMM
    gemm_x3<<<dim3(6, 38), 256, 0, stream>>>(output, qpos, woa_h + (size_t)i * 98304,
                                             woa_l + (size_t)i * 98304,
                                             boffattn + i * 384, offaw, kBQ, 384, 384, 256, 0);
    softmax16_kernel<<<(kBQ * kH + 255) / 256, 256, 0, stream>>>(offaw);
    gemm_val<<<1063, 256, 0, stream>>>(memory, wv_h + (size_t)i * 65536,
                                       ca_bv + i * kC, val_bf, kB * kS);
    msda_kernel<<<kBQ, 256, 0, stream>>>(val_bf, offaw, ref, vr, head);
    gemm_x3<<<dim3(4, 38), 256, 0, stream>>>(head, nullptr, wout_h + (size_t)i * 65536,
                                             wout_l + (size_t)i * 65536,
                                             ca_bout + i * kC, tmp, kBQ, 256, 256, 256, 0);
    ln_kernel<<<kBQ, 256, 0, stream>>>(output, tmp, ln2_g + i * kC, ln2_b + i * kC, output);
    // FFN
    gemm_x3<<<dim3(16, 38), 256, 0, stream>>>(output, nullptr, w1_h + (size_t)i * 262144,
                                              w1_l + (size_t)i * 262144,
                                              ffn_b1 + i * kF, ffnh, kBQ, kF, kF, 256, 1);
    gemm_x3<<<dim3(4, 38), 256, 0, stream>>>(ffnh, nullptr, w2_h + (size_t)i * 262144,
                                             w2_l + (size_t)i * 262144,
                                             ffn_b2 + i * kC, tmp, kBQ, 256, 256, kF, 0);
    ln_kernel<<<kBQ, 256, 0, stream>>>(output, tmp, ln3_g + i * kC, ln3_b + i * kC, output);
    // heads: merged box1+cls dual GEMM
    ln_kernel<<<kBQ, 256, 0, stream>>>(output, nullptr, norm_g, norm_b, nob);
    gemm_x3_dual<<<dim3(6, 38), 256, 0, stream>>>(nob, wbc_h + (size_t)i * 98304,
                                                  wbc_l + (size_t)i * 98304,
                                                  bboxcls + i * 384,
                                                  bh1, 256,
                                                  logits_out + (size_t)i * kBQ * kNC, kNC,
                                                  kBQ, 256);
    gemm_x3<<<dim3(4, 38), 256, 0, stream>>>(bh1, nullptr, wb2_h + (size_t)i * 65536,
                                             wb2_l + (size_t)i * 65536,
                                             box_b2 + i * kC, bh2, kBQ, 256, 256, 256, 1);
    box_final<<<(kBQ * 4 + 255) / 256, 256, 0, stream>>>(bh2, box_W3 + (size_t)i * kC * 4,
                                                         box_b3 + i * 4, ref,
                                                         boxes_out + (size_t)i * kBQ * 4);
    ref = boxes_out + (size_t)i * kBQ * 4;
  }
}